// Round 1
// baseline (1084.066 us; speedup 1.0000x reference)
//
#include <hip/hip_runtime.h>

// ---------- helpers ----------
__device__ __forceinline__ long ld_idx(const void* idx, long pos, int is64) {
  return is64 ? (long)((const long long*)idx)[pos]
              : (long)((const int*)idx)[pos];
}

// Detect whether edge_index is int64 (flag=1) or int32 (flag=0).
// int64 indices are all < 2^32; int32 data read as u64 gives hi-word = next index,
// which is >= 2^32 unless that index is 0 (prob ~0 across 256 samples).
__global__ void k_detect(const unsigned long long* __restrict__ p, int* __restrict__ flag) {
  if (threadIdx.x == 0) *flag = 1;
  __syncthreads();
  if (p[threadIdx.x] >= (1ULL << 32)) atomicExch(flag, 0);
}

__global__ void k_fill1(float* __restrict__ p, long n) {
  long i = (long)blockIdx.x * blockDim.x + threadIdx.x;
  if (i < n) p[i] = 1.0f;  // self-loop weight
}

__global__ void k_deg(const void* __restrict__ idx, const int* __restrict__ flag,
                      const float* __restrict__ w, float* __restrict__ deg, long E) {
  long e = (long)blockIdx.x * blockDim.x + threadIdx.x;
  if (e >= E) return;
  long d = ld_idx(idx, E + e, *flag);
  unsafeAtomicAdd(&deg[d], w[e]);
}

__global__ void k_rsqrt(float* __restrict__ deg, long n) {
  long i = (long)blockIdx.x * blockDim.x + threadIdx.x;
  if (i >= n) return;
  float v = deg[i];
  deg[i] = (v > 0.0f) ? rsqrtf(v) : 0.0f;
}

// h[n,64] = X[n,128] @ W[128,64]; W staged in LDS, 4 nodes / 256-thread block
__global__ __launch_bounds__(256) void k_gemm1(const float* __restrict__ X,
                                               const float* __restrict__ W,
                                               float* __restrict__ h, int n) {
  __shared__ float Ws[128 * 64];
  for (int i = threadIdx.x; i < 128 * 64; i += 256) Ws[i] = W[i];
  __syncthreads();
  int f = threadIdx.x & 63;
  int node = blockIdx.x * 4 + (threadIdx.x >> 6);
  if (node >= n) return;
  const float4* xr = (const float4*)(X + (long)node * 128);
  float acc = 0.0f;
#pragma unroll
  for (int k4 = 0; k4 < 32; ++k4) {
    float4 x = xr[k4];
    acc = fmaf(x.x, Ws[(k4 * 4 + 0) * 64 + f], acc);
    acc = fmaf(x.y, Ws[(k4 * 4 + 1) * 64 + f], acc);
    acc = fmaf(x.z, Ws[(k4 * 4 + 2) * 64 + f], acc);
    acc = fmaf(x.w, Ws[(k4 * 4 + 3) * 64 + f], acc);
  }
  h[(long)node * 64 + f] = acc;
}

// out[i*64+f] = b[f] + h[i*64+f] * dis[i]^2   (bias + self-loop message)
__global__ void k_init_out(const float* __restrict__ h, const float* __restrict__ dis,
                           const float* __restrict__ b, float* __restrict__ out, long n64) {
  long i = (long)blockIdx.x * blockDim.x + threadIdx.x;
  if (i >= n64) return;
  long node = i >> 6;
  int f = (int)(i & 63);
  float s = dis[node];
  out[i] = b[f] + h[i] * s * s;
}

// one wave per edge, lane = feature; atomic scatter-add at dst
__global__ __launch_bounds__(256) void k_scatter(const float* __restrict__ h,
                                                 const float* __restrict__ dis,
                                                 const float* __restrict__ w,
                                                 const void* __restrict__ idx,
                                                 const int* __restrict__ flag,
                                                 float* __restrict__ out, long E) {
  int lane = threadIdx.x & 63;
  long e = (long)blockIdx.x * 4 + (threadIdx.x >> 6);
  if (e >= E) return;
  int is64 = *flag;
  long s = ld_idx(idx, e, is64);
  long d = ld_idx(idx, E + e, is64);
  float nrm = dis[s] * w[e] * dis[d];
  unsafeAtomicAdd(&out[d * 64 + lane], h[s * 64 + lane] * nrm);
}

// h[n,64] = relu(in[n,64]) @ W[64,64]
__global__ __launch_bounds__(256) void k_gemm2(const float* __restrict__ in,
                                               const float* __restrict__ W,
                                               float* __restrict__ h, int n) {
  __shared__ float Ws[64 * 64];
  for (int i = threadIdx.x; i < 64 * 64; i += 256) Ws[i] = W[i];
  __syncthreads();
  int f = threadIdx.x & 63;
  int node = blockIdx.x * 4 + (threadIdx.x >> 6);
  if (node >= n) return;
  const float4* xr = (const float4*)(in + (long)node * 64);
  float acc = 0.0f;
#pragma unroll
  for (int k4 = 0; k4 < 16; ++k4) {
    float4 x = xr[k4];
    acc = fmaf(fmaxf(x.x, 0.0f), Ws[(k4 * 4 + 0) * 64 + f], acc);
    acc = fmaf(fmaxf(x.y, 0.0f), Ws[(k4 * 4 + 1) * 64 + f], acc);
    acc = fmaf(fmaxf(x.z, 0.0f), Ws[(k4 * 4 + 2) * 64 + f], acc);
    acc = fmaf(fmaxf(x.w, 0.0f), Ws[(k4 * 4 + 3) * 64 + f], acc);
  }
  h[(long)node * 64 + f] = acc;
}

// out[i] = sigmoid( relu(in[i,:]) . Wl + bl ); one wave per node
__global__ void k_final(const float* __restrict__ in, const float* __restrict__ Wl,
                        const float* __restrict__ bl, float* __restrict__ out, int n) {
  int lane = threadIdx.x & 63;
  int node = blockIdx.x * 4 + (threadIdx.x >> 6);
  if (node >= n) return;
  float v = fmaxf(in[(long)node * 64 + lane], 0.0f) * Wl[lane];
#pragma unroll
  for (int off = 32; off > 0; off >>= 1) v += __shfl_down(v, off);
  if (lane == 0) out[node] = 1.0f / (1.0f + expf(-(v + bl[0])));
}

extern "C" void kernel_launch(void* const* d_in, const int* in_sizes, int n_in,
                              void* d_out, int out_size, void* d_ws, size_t ws_size,
                              hipStream_t stream) {
  const float* X  = (const float*)d_in[0];
  const void*  EI = d_in[1];
  const float* EW = (const float*)d_in[2];
  const float* W1 = (const float*)d_in[3];
  const float* b1 = (const float*)d_in[4];
  const float* W2 = (const float*)d_in[5];
  const float* b2 = (const float*)d_in[6];
  const float* Wl = (const float*)d_in[7];
  const float* bl = (const float*)d_in[8];
  float* out = (float*)d_out;

  const int  n = in_sizes[0] / 128;   // 50000
  const long E = (long)in_sizes[1] / 2;  // 1,600,000

  // workspace layout: [flag(256B)] [dis: n floats] [A: n*64] [B: n*64]  (~26 MB)
  char* ws = (char*)d_ws;
  int*   flag = (int*)ws;
  float* dis  = (float*)(ws + 256);
  size_t off  = 256 + (((size_t)n * 4 + 255) / 256) * 256;
  float* A = (float*)(ws + off);        // h1, then h2
  off += (size_t)n * 64 * 4;
  float* B = (float*)(ws + off);        // out1, then out2

  const long n64 = (long)n * 64;
  dim3 blk(256);

  k_detect<<<1, 256, 0, stream>>>((const unsigned long long*)EI, flag);
  k_fill1<<<(int)((n + 255) / 256), blk, 0, stream>>>(dis, n);
  k_deg<<<(int)((E + 255) / 256), blk, 0, stream>>>(EI, flag, EW, dis, E);
  k_rsqrt<<<(int)((n + 255) / 256), blk, 0, stream>>>(dis, n);

  // layer 1
  k_gemm1<<<(int)((n + 3) / 4), blk, 0, stream>>>(X, W1, A, n);
  k_init_out<<<(int)((n64 + 255) / 256), blk, 0, stream>>>(A, dis, b1, B, n64);
  k_scatter<<<(int)((E + 3) / 4), blk, 0, stream>>>(A, dis, EW, EI, flag, B, E);

  // layer 2 (relu fused into gemm2 read)
  k_gemm2<<<(int)((n + 3) / 4), blk, 0, stream>>>(B, W2, A, n);
  k_init_out<<<(int)((n64 + 255) / 256), blk, 0, stream>>>(A, dis, b2, B, n64);
  k_scatter<<<(int)((E + 3) / 4), blk, 0, stream>>>(A, dis, EW, EI, flag, B, E);

  // readout (relu fused)
  k_final<<<(int)((n + 3) / 4), blk, 0, stream>>>(B, Wl, bl, out, n);
}

// Round 2
// 707.218 us; speedup vs baseline: 1.5329x; 1.5329x over previous
//
#include <hip/hip_runtime.h>

// ---------- helpers ----------
__device__ __forceinline__ long ld_idx(const void* idx, long pos, int is64) {
  return is64 ? (long)((const long long*)idx)[pos]
              : (long)((const int*)idx)[pos];
}

// Detect whether edge_index is int64 (flag=1) or int32 (flag=0).
__global__ void k_detect(const unsigned long long* __restrict__ p, int* __restrict__ flag) {
  if (threadIdx.x == 0) *flag = 1;
  __syncthreads();
  if (p[threadIdx.x] >= (1ULL << 32)) atomicExch(flag, 0);
}

// deg = 1.0 (self-loop weight), count = 0
__global__ void k_init_nodes(float* __restrict__ deg, int* __restrict__ count, long n) {
  long i = (long)blockIdx.x * blockDim.x + threadIdx.x;
  if (i < n) { deg[i] = 1.0f; count[i] = 0; }
}

// weighted degree + in-degree histogram at dst
__global__ void k_deg_hist(const void* __restrict__ idx, const int* __restrict__ flag,
                           const float* __restrict__ w, float* __restrict__ deg,
                           int* __restrict__ count, long E) {
  long e = (long)blockIdx.x * blockDim.x + threadIdx.x;
  if (e >= E) return;
  long d = ld_idx(idx, E + e, *flag);
  unsafeAtomicAdd(&deg[d], w[e]);
  atomicAdd(&count[d], 1);
}

__global__ void k_rsqrt(float* __restrict__ deg, long n) {
  long i = (long)blockIdx.x * blockDim.x + threadIdx.x;
  if (i >= n) return;
  float v = deg[i];
  deg[i] = (v > 0.0f) ? rsqrtf(v) : 0.0f;
}

// ---------- scan (exclusive prefix sum of count -> rowptr, next) ----------
// s1: per-block (1024-elem chunk) sums
__global__ __launch_bounds__(256) void k_scansum(const int* __restrict__ count, int* __restrict__ bsum, int n) {
  __shared__ int sh[256];
  int t = threadIdx.x;
  int base = blockIdx.x * 1024 + t * 4;
  int s = 0;
#pragma unroll
  for (int k = 0; k < 4; ++k) { int i = base + k; if (i < n) s += count[i]; }
  sh[t] = s; __syncthreads();
  for (int off = 128; off > 0; off >>= 1) {
    if (t < off) sh[t] += sh[t + off];
    __syncthreads();
  }
  if (t == 0) bsum[blockIdx.x] = sh[0];
}

// s2: single-wave exclusive scan of block sums (nb <= 64); writes rowptr[n]=total
__global__ void k_scanoffsets(int* __restrict__ bsum, int* __restrict__ rowptr, int nb, int n) {
  int t = threadIdx.x;  // 64 threads
  int v = (t < nb) ? bsum[t] : 0;
  int inc = v;
#pragma unroll
  for (int off = 1; off < 64; off <<= 1) {
    int u = __shfl_up(inc, off);
    if (t >= off) inc += u;
  }
  if (t < nb) bsum[t] = inc - v;      // exclusive
  if (t == nb - 1) rowptr[n] = inc;   // total = E
}

// s3: local exclusive scan within chunk + block offset -> rowptr & next
__global__ __launch_bounds__(256) void k_scanwrite(const int* __restrict__ count,
                                                   const int* __restrict__ bsum,
                                                   int* __restrict__ rowptr,
                                                   int* __restrict__ next, int n) {
  __shared__ int sh[256];
  int t = threadIdx.x;
  int base = blockIdx.x * 1024 + t * 4;
  int c[4]; int s = 0;
#pragma unroll
  for (int k = 0; k < 4; ++k) { int i = base + k; c[k] = (i < n) ? count[i] : 0; s += c[k]; }
  sh[t] = s; __syncthreads();
  // Hillis-Steele inclusive scan over thread sums
  for (int off = 1; off < 256; off <<= 1) {
    int u = (t >= off) ? sh[t - off] : 0;
    __syncthreads();
    sh[t] += u;
    __syncthreads();
  }
  int excl = sh[t] - s + bsum[blockIdx.x];
#pragma unroll
  for (int k = 0; k < 4; ++k) {
    int i = base + k;
    if (i < n) { rowptr[i] = excl; next[i] = excl; }
    excl += c[k];
  }
}

// ---------- permute edges into CSR-by-dst, payload = (src, norm) ----------
__global__ void k_permute(const void* __restrict__ idx, const int* __restrict__ flag,
                          const float* __restrict__ w, const float* __restrict__ dis,
                          int* __restrict__ next, float2* __restrict__ edges, long E) {
  long e = (long)blockIdx.x * blockDim.x + threadIdx.x;
  if (e >= E) return;
  int is64 = *flag;
  long s = ld_idx(idx, e, is64);
  long d = ld_idx(idx, E + e, is64);
  float nrm = dis[s] * w[e] * dis[d];
  int pos = atomicAdd(&next[d], 1);
  edges[pos] = make_float2(__int_as_float((int)s), nrm);
}

// ---------- dense layers ----------
// h[n,64] = X[n,128] @ W[128,64]
__global__ __launch_bounds__(256) void k_gemm1(const float* __restrict__ X,
                                               const float* __restrict__ W,
                                               float* __restrict__ h, int n) {
  __shared__ float Ws[128 * 64];
  for (int i = threadIdx.x; i < 128 * 64; i += 256) Ws[i] = W[i];
  __syncthreads();
  int f = threadIdx.x & 63;
  int node = blockIdx.x * 4 + (threadIdx.x >> 6);
  if (node >= n) return;
  const float4* xr = (const float4*)(X + (long)node * 128);
  float acc = 0.0f;
#pragma unroll
  for (int k4 = 0; k4 < 32; ++k4) {
    float4 x = xr[k4];
    acc = fmaf(x.x, Ws[(k4 * 4 + 0) * 64 + f], acc);
    acc = fmaf(x.y, Ws[(k4 * 4 + 1) * 64 + f], acc);
    acc = fmaf(x.z, Ws[(k4 * 4 + 2) * 64 + f], acc);
    acc = fmaf(x.w, Ws[(k4 * 4 + 3) * 64 + f], acc);
  }
  h[(long)node * 64 + f] = acc;
}

// h[n,64] = relu(in[n,64]) @ W[64,64]
__global__ __launch_bounds__(256) void k_gemm2(const float* __restrict__ in,
                                               const float* __restrict__ W,
                                               float* __restrict__ h, int n) {
  __shared__ float Ws[64 * 64];
  for (int i = threadIdx.x; i < 64 * 64; i += 256) Ws[i] = W[i];
  __syncthreads();
  int f = threadIdx.x & 63;
  int node = blockIdx.x * 4 + (threadIdx.x >> 6);
  if (node >= n) return;
  const float4* xr = (const float4*)(in + (long)node * 64);
  float acc = 0.0f;
#pragma unroll
  for (int k4 = 0; k4 < 16; ++k4) {
    float4 x = xr[k4];
    acc = fmaf(fmaxf(x.x, 0.0f), Ws[(k4 * 4 + 0) * 64 + f], acc);
    acc = fmaf(fmaxf(x.y, 0.0f), Ws[(k4 * 4 + 1) * 64 + f], acc);
    acc = fmaf(fmaxf(x.z, 0.0f), Ws[(k4 * 4 + 2) * 64 + f], acc);
    acc = fmaf(fmaxf(x.w, 0.0f), Ws[(k4 * 4 + 3) * 64 + f], acc);
  }
  h[(long)node * 64 + f] = acc;
}

// ---------- pull-gather: one wave per dst node, lane = feature ----------
__global__ __launch_bounds__(256) void k_gather(const float* __restrict__ h,
                                                const float* __restrict__ dis,
                                                const float2* __restrict__ edges,
                                                const int* __restrict__ rowptr,
                                                const float* __restrict__ b,
                                                float* __restrict__ out, int n) {
  int lane = threadIdx.x & 63;
  int node = blockIdx.x * 4 + (threadIdx.x >> 6);
  if (node >= n) return;
  int beg = rowptr[node], end = rowptr[node + 1];
  float s0 = dis[node];
  float acc = b[lane] + h[(long)node * 64 + lane] * s0 * s0;  // bias + self-loop
  int deg = end - beg;
  int nfull = deg >> 6;
  int base = beg;
  for (int f = 0; f < nfull; ++f, base += 64) {
    float2 pk = edges[base + lane];   // 64 edges staged across lanes
#pragma unroll
    for (int j = 0; j < 64; ++j) {
      int   sj = __float_as_int(__shfl(pk.x, j));
      float nj = __shfl(pk.y, j);
      acc = fmaf(h[(long)sj * 64 + lane], nj, acc);
    }
  }
  int m = end - base;
  if (m > 0) {
    float2 pk = (lane < m) ? edges[base + lane] : make_float2(0.0f, 0.0f);
    for (int j = 0; j < m; ++j) {
      int   sj = __float_as_int(__shfl(pk.x, j));
      float nj = __shfl(pk.y, j);
      acc = fmaf(h[(long)sj * 64 + lane], nj, acc);
    }
  }
  out[(long)node * 64 + lane] = acc;
}

// out[i] = sigmoid( relu(in[i,:]) . Wl + bl ); one wave per node
__global__ void k_final(const float* __restrict__ in, const float* __restrict__ Wl,
                        const float* __restrict__ bl, float* __restrict__ out, int n) {
  int lane = threadIdx.x & 63;
  int node = blockIdx.x * 4 + (threadIdx.x >> 6);
  if (node >= n) return;
  float v = fmaxf(in[(long)node * 64 + lane], 0.0f) * Wl[lane];
#pragma unroll
  for (int off = 32; off > 0; off >>= 1) v += __shfl_down(v, off);
  if (lane == 0) out[node] = 1.0f / (1.0f + expf(-(v + bl[0])));
}

extern "C" void kernel_launch(void* const* d_in, const int* in_sizes, int n_in,
                              void* d_out, int out_size, void* d_ws, size_t ws_size,
                              hipStream_t stream) {
  const float* X  = (const float*)d_in[0];
  const void*  EI = d_in[1];
  const float* EW = (const float*)d_in[2];
  const float* W1 = (const float*)d_in[3];
  const float* b1 = (const float*)d_in[4];
  const float* W2 = (const float*)d_in[5];
  const float* b2 = (const float*)d_in[6];
  const float* Wl = (const float*)d_in[7];
  const float* bl = (const float*)d_in[8];
  float* out = (float*)d_out;

  const int  n = in_sizes[0] / 128;      // 50000
  const long E = (long)in_sizes[1] / 2;  // 1,600,000

  auto align = [](size_t x) { return (x + 255) & ~(size_t)255; };
  char* ws = (char*)d_ws;
  size_t off = 0;
  int*    flag   = (int*)(ws + off);    off += 256;
  float*  dis    = (float*)(ws + off);  off += align((size_t)n * 4);
  int*    count  = (int*)(ws + off);    off += align((size_t)n * 4);
  int*    rowptr = (int*)(ws + off);    off += align((size_t)(n + 1) * 4);
  int*    next   = (int*)(ws + off);    off += align((size_t)n * 4);
  int*    bsum   = (int*)(ws + off);    off += 256;
  float2* edges  = (float2*)(ws + off); off += align((size_t)E * 8);
  float*  A      = (float*)(ws + off);  off += align((size_t)n * 64 * 4);
  float*  B      = (float*)(ws + off);  off += align((size_t)n * 64 * 4);

  dim3 blk(256);
  const int nbN = (n + 255) / 256;
  const int nbE = (int)((E + 255) / 256);
  const int nb  = (n + 1023) / 1024;    // scan chunks (<=64)

  k_detect<<<1, 256, 0, stream>>>((const unsigned long long*)EI, flag);
  k_init_nodes<<<nbN, blk, 0, stream>>>(dis, count, n);
  k_deg_hist<<<nbE, blk, 0, stream>>>(EI, flag, EW, dis, count, E);
  k_rsqrt<<<nbN, blk, 0, stream>>>(dis, n);

  // CSR build
  k_scansum<<<nb, blk, 0, stream>>>(count, bsum, n);
  k_scanoffsets<<<1, 64, 0, stream>>>(bsum, rowptr, nb, n);
  k_scanwrite<<<nb, blk, 0, stream>>>(count, bsum, rowptr, next, n);
  k_permute<<<nbE, blk, 0, stream>>>(EI, flag, EW, dis, next, edges, E);

  // layer 1
  k_gemm1<<<(n + 3) / 4, blk, 0, stream>>>(X, W1, A, n);
  k_gather<<<(n + 3) / 4, blk, 0, stream>>>(A, dis, edges, rowptr, b1, B, n);

  // layer 2 (relu fused into gemm2 read)
  k_gemm2<<<(n + 3) / 4, blk, 0, stream>>>(B, W2, A, n);
  k_gather<<<(n + 3) / 4, blk, 0, stream>>>(A, dis, edges, rowptr, b2, B, n);

  // readout (relu fused)
  k_final<<<(n + 3) / 4, blk, 0, stream>>>(B, Wl, bl, out, n);
}

// Round 3
// 649.450 us; speedup vs baseline: 1.6692x; 1.0890x over previous
//
#include <hip/hip_runtime.h>

// ---------- helpers ----------
__device__ __forceinline__ long ld_idx(const void* idx, long pos, int is64) {
  return is64 ? (long)((const long long*)idx)[pos]
              : (long)((const int*)idx)[pos];
}

// Detect whether edge_index is int64 (flag=1) or int32 (flag=0).
__global__ void k_detect(const unsigned long long* __restrict__ p, int* __restrict__ flag) {
  if (threadIdx.x == 0) *flag = 1;
  __syncthreads();
  if (p[threadIdx.x] >= (1ULL << 32)) atomicExch(flag, 0);
}

__global__ void k_zero(int* __restrict__ p, long n) {
  long i = (long)blockIdx.x * blockDim.x + threadIdx.x;
  if (i < n) p[i] = 0;
}

// in-degree histogram at dst; slot[e] = position of edge e within its dst row
__global__ void k_hist(const void* __restrict__ idx, const int* __restrict__ flag,
                       int* __restrict__ count, unsigned short* __restrict__ slot, long E) {
  long e = (long)blockIdx.x * blockDim.x + threadIdx.x;
  if (e >= E) return;
  long d = ld_idx(idx, E + e, *flag);
  slot[e] = (unsigned short)atomicAdd(&count[d], 1);
}

// ---------- scan (exclusive prefix sum of count -> rowptr) ----------
__global__ __launch_bounds__(256) void k_scansum(const int* __restrict__ count, int* __restrict__ bsum, int n) {
  __shared__ int sh[256];
  int t = threadIdx.x;
  int base = blockIdx.x * 1024 + t * 4;
  int s = 0;
#pragma unroll
  for (int k = 0; k < 4; ++k) { int i = base + k; if (i < n) s += count[i]; }
  sh[t] = s; __syncthreads();
  for (int off = 128; off > 0; off >>= 1) {
    if (t < off) sh[t] += sh[t + off];
    __syncthreads();
  }
  if (t == 0) bsum[blockIdx.x] = sh[0];
}

__global__ void k_scanoffsets(int* __restrict__ bsum, int* __restrict__ rowptr, int nb, int n) {
  int t = threadIdx.x;  // 64 threads
  int v = (t < nb) ? bsum[t] : 0;
  int inc = v;
#pragma unroll
  for (int off = 1; off < 64; off <<= 1) {
    int u = __shfl_up(inc, off);
    if (t >= off) inc += u;
  }
  if (t < nb) bsum[t] = inc - v;      // exclusive
  if (t == nb - 1) rowptr[n] = inc;   // total = E
}

__global__ __launch_bounds__(256) void k_scanwrite(const int* __restrict__ count,
                                                   const int* __restrict__ bsum,
                                                   int* __restrict__ rowptr, int n) {
  __shared__ int sh[256];
  int t = threadIdx.x;
  int base = blockIdx.x * 1024 + t * 4;
  int c[4]; int s = 0;
#pragma unroll
  for (int k = 0; k < 4; ++k) { int i = base + k; c[k] = (i < n) ? count[i] : 0; s += c[k]; }
  sh[t] = s; __syncthreads();
  for (int off = 1; off < 256; off <<= 1) {
    int u = (t >= off) ? sh[t - off] : 0;
    __syncthreads();
    sh[t] += u;
    __syncthreads();
  }
  int excl = sh[t] - s + bsum[blockIdx.x];
#pragma unroll
  for (int k = 0; k < 4; ++k) {
    int i = base + k;
    if (i < n) rowptr[i] = excl;
    excl += c[k];
  }
}

// ---------- permute edges into CSR-by-dst (atomic-free), payload = (src, w) ----------
__global__ void k_permute(const void* __restrict__ idx, const int* __restrict__ flag,
                          const float* __restrict__ w, const int* __restrict__ rowptr,
                          const unsigned short* __restrict__ slot,
                          float2* __restrict__ edges, long E) {
  long e = (long)blockIdx.x * blockDim.x + threadIdx.x;
  if (e >= E) return;
  int is64 = *flag;
  long s = ld_idx(idx, e, is64);
  long d = ld_idx(idx, E + e, is64);
  edges[rowptr[d] + (int)slot[e]] = make_float2(__int_as_float((int)s), w[e]);
}

// ---------- weighted degree from CSR rows + fused rsqrt: dis[i] = rsqrt(1 + sum w) ----------
__global__ __launch_bounds__(256) void k_deg_rsqrt(const float2* __restrict__ edges,
                                                   const int* __restrict__ rowptr,
                                                   float* __restrict__ dis, int n) {
  int lane = threadIdx.x & 63;
  int node = blockIdx.x * 4 + (threadIdx.x >> 6);
  if (node >= n) return;
  int beg = rowptr[node], end = rowptr[node + 1];
  float s = 0.0f;
  for (int i = beg + lane; i < end; i += 64) s += edges[i].y;
#pragma unroll
  for (int off = 32; off > 0; off >>= 1) s += __shfl_down(s, off);
  if (lane == 0) dis[node] = rsqrtf(1.0f + s);   // deg >= 1 always (self-loop)
}

// ---------- dense layers ----------
__global__ __launch_bounds__(256) void k_gemm1(const float* __restrict__ X,
                                               const float* __restrict__ W,
                                               float* __restrict__ h, int n) {
  __shared__ float Ws[128 * 64];
  for (int i = threadIdx.x; i < 128 * 64; i += 256) Ws[i] = W[i];
  __syncthreads();
  int f = threadIdx.x & 63;
  int node = blockIdx.x * 4 + (threadIdx.x >> 6);
  if (node >= n) return;
  const float4* xr = (const float4*)(X + (long)node * 128);
  float acc = 0.0f;
#pragma unroll
  for (int k4 = 0; k4 < 32; ++k4) {
    float4 x = xr[k4];
    acc = fmaf(x.x, Ws[(k4 * 4 + 0) * 64 + f], acc);
    acc = fmaf(x.y, Ws[(k4 * 4 + 1) * 64 + f], acc);
    acc = fmaf(x.z, Ws[(k4 * 4 + 2) * 64 + f], acc);
    acc = fmaf(x.w, Ws[(k4 * 4 + 3) * 64 + f], acc);
  }
  h[(long)node * 64 + f] = acc;
}

__global__ __launch_bounds__(256) void k_gemm2(const float* __restrict__ in,
                                               const float* __restrict__ W,
                                               float* __restrict__ h, int n) {
  __shared__ float Ws[64 * 64];
  for (int i = threadIdx.x; i < 64 * 64; i += 256) Ws[i] = W[i];
  __syncthreads();
  int f = threadIdx.x & 63;
  int node = blockIdx.x * 4 + (threadIdx.x >> 6);
  if (node >= n) return;
  const float4* xr = (const float4*)(in + (long)node * 64);
  float acc = 0.0f;
#pragma unroll
  for (int k4 = 0; k4 < 16; ++k4) {
    float4 x = xr[k4];
    acc = fmaf(fmaxf(x.x, 0.0f), Ws[(k4 * 4 + 0) * 64 + f], acc);
    acc = fmaf(fmaxf(x.y, 0.0f), Ws[(k4 * 4 + 1) * 64 + f], acc);
    acc = fmaf(fmaxf(x.z, 0.0f), Ws[(k4 * 4 + 2) * 64 + f], acc);
    acc = fmaf(fmaxf(x.w, 0.0f), Ws[(k4 * 4 + 3) * 64 + f], acc);
  }
  h[(long)node * 64 + f] = acc;
}

// ---------- pull-gather: one wave per dst node, lane = feature; norm on the fly ----------
__global__ __launch_bounds__(256) void k_gather(const float* __restrict__ h,
                                                const float* __restrict__ dis,
                                                const float2* __restrict__ edges,
                                                const int* __restrict__ rowptr,
                                                const float* __restrict__ b,
                                                float* __restrict__ out, int n) {
  int lane = threadIdx.x & 63;
  int node = blockIdx.x * 4 + (threadIdx.x >> 6);
  if (node >= n) return;
  int beg = rowptr[node], end = rowptr[node + 1];
  float s0 = dis[node];
  float acc = b[lane] + h[(long)node * 64 + lane] * s0 * s0;  // bias + self-loop
  int deg = end - beg;
  int nfull = deg >> 6;
  int base = beg;
  for (int f = 0; f < nfull; ++f, base += 64) {
    float2 pk = edges[base + lane];                   // 64 edges staged across lanes
    float nrm = dis[__float_as_int(pk.x)] * pk.y * s0;
#pragma unroll
    for (int j = 0; j < 64; ++j) {
      int   sj = __float_as_int(__shfl(pk.x, j));
      float nj = __shfl(nrm, j);
      acc = fmaf(h[(long)sj * 64 + lane], nj, acc);
    }
  }
  int m = end - base;
  if (m > 0) {
    float2 pk = (lane < m) ? edges[base + lane] : make_float2(0.0f, 0.0f);
    float nrm = dis[__float_as_int(pk.x)] * pk.y * s0;
    for (int j = 0; j < m; ++j) {
      int   sj = __float_as_int(__shfl(pk.x, j));
      float nj = __shfl(nrm, j);
      acc = fmaf(h[(long)sj * 64 + lane], nj, acc);
    }
  }
  out[(long)node * 64 + lane] = acc;
}

// out[i] = sigmoid( relu(in[i,:]) . Wl + bl ); one wave per node
__global__ void k_final(const float* __restrict__ in, const float* __restrict__ Wl,
                        const float* __restrict__ bl, float* __restrict__ out, int n) {
  int lane = threadIdx.x & 63;
  int node = blockIdx.x * 4 + (threadIdx.x >> 6);
  if (node >= n) return;
  float v = fmaxf(in[(long)node * 64 + lane], 0.0f) * Wl[lane];
#pragma unroll
  for (int off = 32; off > 0; off >>= 1) v += __shfl_down(v, off);
  if (lane == 0) out[node] = 1.0f / (1.0f + expf(-(v + bl[0])));
}

extern "C" void kernel_launch(void* const* d_in, const int* in_sizes, int n_in,
                              void* d_out, int out_size, void* d_ws, size_t ws_size,
                              hipStream_t stream) {
  const float* X  = (const float*)d_in[0];
  const void*  EI = d_in[1];
  const float* EW = (const float*)d_in[2];
  const float* W1 = (const float*)d_in[3];
  const float* b1 = (const float*)d_in[4];
  const float* W2 = (const float*)d_in[5];
  const float* b2 = (const float*)d_in[6];
  const float* Wl = (const float*)d_in[7];
  const float* bl = (const float*)d_in[8];
  float* out = (float*)d_out;

  const int  n = in_sizes[0] / 128;      // 50000
  const long E = (long)in_sizes[1] / 2;  // 1,600,000

  auto align = [](size_t x) { return (x + 255) & ~(size_t)255; };
  char* ws = (char*)d_ws;
  size_t off = 0;
  int*            flag   = (int*)(ws + off);            off += 256;
  float*          dis    = (float*)(ws + off);          off += align((size_t)n * 4);
  int*            count  = (int*)(ws + off);            off += align((size_t)n * 4);
  int*            rowptr = (int*)(ws + off);            off += align((size_t)(n + 1) * 4);
  int*            bsum   = (int*)(ws + off);            off += 256;
  unsigned short* slot   = (unsigned short*)(ws + off); off += align((size_t)E * 2);
  float2*         edges  = (float2*)(ws + off);         off += align((size_t)E * 8);
  float*          A      = (float*)(ws + off);          off += align((size_t)n * 64 * 4);
  float*          B      = (float*)(ws + off);          off += align((size_t)n * 64 * 4);

  dim3 blk(256);
  const int nbN = (n + 255) / 256;
  const int nbE = (int)((E + 255) / 256);
  const int nb  = (n + 1023) / 1024;    // scan chunks (<=64)
  const int nbW = (n + 3) / 4;          // 4 waves/block kernels

  k_detect<<<1, 256, 0, stream>>>((const unsigned long long*)EI, flag);
  k_zero<<<nbN, blk, 0, stream>>>(count, n);
  k_hist<<<nbE, blk, 0, stream>>>(EI, flag, count, slot, E);

  // CSR build
  k_scansum<<<nb, blk, 0, stream>>>(count, bsum, n);
  k_scanoffsets<<<1, 64, 0, stream>>>(bsum, rowptr, nb, n);
  k_scanwrite<<<nb, blk, 0, stream>>>(count, bsum, rowptr, n);
  k_permute<<<nbE, blk, 0, stream>>>(EI, flag, EW, rowptr, slot, edges, E);

  // degree + rsqrt from CSR rows
  k_deg_rsqrt<<<nbW, blk, 0, stream>>>(edges, rowptr, dis, n);

  // layer 1
  k_gemm1<<<nbW, blk, 0, stream>>>(X, W1, A, n);
  k_gather<<<nbW, blk, 0, stream>>>(A, dis, edges, rowptr, b1, B, n);

  // layer 2 (relu fused into gemm2 read)
  k_gemm2<<<nbW, blk, 0, stream>>>(B, W2, A, n);
  k_gather<<<nbW, blk, 0, stream>>>(A, dis, edges, rowptr, b2, B, n);

  // readout (relu fused)
  k_final<<<nbW, blk, 0, stream>>>(B, Wl, bl, out, n);
}

// Round 4
// 383.415 us; speedup vs baseline: 2.8274x; 1.6939x over previous
//
#include <hip/hip_runtime.h>

typedef _Float16 half4 __attribute__((ext_vector_type(4)));

// ---------- helpers ----------
__device__ __forceinline__ long ld_idx(const void* idx, long pos, int is64) {
  return is64 ? (long)((const long long*)idx)[pos]
              : (long)((const int*)idx)[pos];
}

// Detect whether edge_index is int64 (flag=1) or int32 (flag=0).
__global__ void k_detect(const unsigned long long* __restrict__ p, int* __restrict__ flag) {
  if (threadIdx.x == 0) *flag = 1;
  __syncthreads();
  if (p[threadIdx.x] >= (1ULL << 32)) atomicExch(flag, 0);
}

__global__ void k_zero(int* __restrict__ p, long n) {
  long i = (long)blockIdx.x * blockDim.x + threadIdx.x;
  if (i < n) p[i] = 0;
}

// in-degree histogram at dst; slot[e] = position of edge e within its dst row
// 2 edges per thread, vectorized index load
__global__ void k_hist(const void* __restrict__ idx, const int* __restrict__ flag,
                       int* __restrict__ count, unsigned short* __restrict__ slot, long E) {
  long e = 2 * ((long)blockIdx.x * blockDim.x + threadIdx.x);
  if (e >= E) return;
  int is64 = *flag;
  long d0, d1 = -1;
  if (is64) {
    const longlong2 dd = *(const longlong2*)((const long long*)idx + E + e);
    d0 = dd.x; d1 = dd.y;
  } else {
    const int2 dd = *(const int2*)((const int*)idx + E + e);
    d0 = dd.x; d1 = dd.y;
  }
  unsigned short s0 = (unsigned short)atomicAdd(&count[d0], 1);
  unsigned short s1 = 0;
  if (e + 1 < E) s1 = (unsigned short)atomicAdd(&count[d1], 1);
  *(ushort2*)(slot + e) = make_ushort2(s0, s1);
}

// ---------- scan (exclusive prefix sum of count -> rowptr) ----------
__global__ __launch_bounds__(256) void k_scansum(const int* __restrict__ count, int* __restrict__ bsum, int n) {
  __shared__ int sh[256];
  int t = threadIdx.x;
  int base = blockIdx.x * 1024 + t * 4;
  int s = 0;
#pragma unroll
  for (int k = 0; k < 4; ++k) { int i = base + k; if (i < n) s += count[i]; }
  sh[t] = s; __syncthreads();
  for (int off = 128; off > 0; off >>= 1) {
    if (t < off) sh[t] += sh[t + off];
    __syncthreads();
  }
  if (t == 0) bsum[blockIdx.x] = sh[0];
}

__global__ void k_scanoffsets(int* __restrict__ bsum, int* __restrict__ rowptr, int nb, int n) {
  int t = threadIdx.x;  // 64 threads
  int v = (t < nb) ? bsum[t] : 0;
  int inc = v;
#pragma unroll
  for (int off = 1; off < 64; off <<= 1) {
    int u = __shfl_up(inc, off);
    if (t >= off) inc += u;
  }
  if (t < nb) bsum[t] = inc - v;      // exclusive
  if (t == nb - 1) rowptr[n] = inc;   // total = E
}

__global__ __launch_bounds__(256) void k_scanwrite(const int* __restrict__ count,
                                                   const int* __restrict__ bsum,
                                                   int* __restrict__ rowptr, int n) {
  __shared__ int sh[256];
  int t = threadIdx.x;
  int base = blockIdx.x * 1024 + t * 4;
  int c[4]; int s = 0;
#pragma unroll
  for (int k = 0; k < 4; ++k) { int i = base + k; c[k] = (i < n) ? count[i] : 0; s += c[k]; }
  sh[t] = s; __syncthreads();
  for (int off = 1; off < 256; off <<= 1) {
    int u = (t >= off) ? sh[t - off] : 0;
    __syncthreads();
    sh[t] += u;
    __syncthreads();
  }
  int excl = sh[t] - s + bsum[blockIdx.x];
#pragma unroll
  for (int k = 0; k < 4; ++k) {
    int i = base + k;
    if (i < n) rowptr[i] = excl;
    excl += c[k];
  }
}

// ---------- permute edges into CSR-by-dst (atomic-free), payload = (src, w) ----------
__global__ void k_permute(const void* __restrict__ idx, const int* __restrict__ flag,
                          const float* __restrict__ w, const int* __restrict__ rowptr,
                          const unsigned short* __restrict__ slot,
                          float2* __restrict__ edges, long E) {
  long e = 2 * ((long)blockIdx.x * blockDim.x + threadIdx.x);
  if (e >= E) return;
  int is64 = *flag;
  long s0, s1 = 0, d0, d1 = 0;
  if (is64) {
    const longlong2 ss = *(const longlong2*)((const long long*)idx + e);
    const longlong2 dd = *(const longlong2*)((const long long*)idx + E + e);
    s0 = ss.x; s1 = ss.y; d0 = dd.x; d1 = dd.y;
  } else {
    const int2 ss = *(const int2*)((const int*)idx + e);
    const int2 dd = *(const int2*)((const int*)idx + E + e);
    s0 = ss.x; s1 = ss.y; d0 = dd.x; d1 = dd.y;
  }
  const ushort2 sl = *(const ushort2*)(slot + e);
  const float2 wv = *(const float2*)(w + e);
  edges[rowptr[d0] + (int)sl.x] = make_float2(__int_as_float((int)s0), wv.x);
  if (e + 1 < E)
    edges[rowptr[d1] + (int)sl.y] = make_float2(__int_as_float((int)s1), wv.y);
}

// ---------- weighted degree from CSR rows + fused rsqrt: dis[i] = rsqrt(1 + sum w) ----------
__global__ __launch_bounds__(256) void k_deg_rsqrt(const float2* __restrict__ edges,
                                                   const int* __restrict__ rowptr,
                                                   float* __restrict__ dis, int n) {
  int lane = threadIdx.x & 63;
  int node = blockIdx.x * 4 + (threadIdx.x >> 6);
  if (node >= n) return;
  int beg = rowptr[node], end = rowptr[node + 1];
  float s = 0.0f;
  for (int i = beg + lane; i < end; i += 64) s += edges[i].y;
#pragma unroll
  for (int off = 32; off > 0; off >>= 1) s += __shfl_down(s, off);
  if (lane == 0) dis[node] = rsqrtf(1.0f + s);   // deg >= 1 always (self-loop)
}

// ---------- dense layers (store fp16) ----------
__global__ __launch_bounds__(256) void k_gemm1(const float* __restrict__ X,
                                               const float* __restrict__ W,
                                               _Float16* __restrict__ h, int n) {
  __shared__ float Ws[128 * 64];
  for (int i = threadIdx.x; i < 128 * 64; i += 256) Ws[i] = W[i];
  __syncthreads();
  int f = threadIdx.x & 63;
  int node = blockIdx.x * 4 + (threadIdx.x >> 6);
  if (node >= n) return;
  const float4* xr = (const float4*)(X + (long)node * 128);
  float acc = 0.0f;
#pragma unroll
  for (int k4 = 0; k4 < 32; ++k4) {
    float4 x = xr[k4];
    acc = fmaf(x.x, Ws[(k4 * 4 + 0) * 64 + f], acc);
    acc = fmaf(x.y, Ws[(k4 * 4 + 1) * 64 + f], acc);
    acc = fmaf(x.z, Ws[(k4 * 4 + 2) * 64 + f], acc);
    acc = fmaf(x.w, Ws[(k4 * 4 + 3) * 64 + f], acc);
  }
  h[(long)node * 64 + f] = (_Float16)acc;
}

// h[n,64] = relu(in[n,64]) @ W[64,64], store fp16
__global__ __launch_bounds__(256) void k_gemm2(const float* __restrict__ in,
                                               const float* __restrict__ W,
                                               _Float16* __restrict__ h, int n) {
  __shared__ float Ws[64 * 64];
  for (int i = threadIdx.x; i < 64 * 64; i += 256) Ws[i] = W[i];
  __syncthreads();
  int f = threadIdx.x & 63;
  int node = blockIdx.x * 4 + (threadIdx.x >> 6);
  if (node >= n) return;
  const float4* xr = (const float4*)(in + (long)node * 64);
  float acc = 0.0f;
#pragma unroll
  for (int k4 = 0; k4 < 16; ++k4) {
    float4 x = xr[k4];
    acc = fmaf(fmaxf(x.x, 0.0f), Ws[(k4 * 4 + 0) * 64 + f], acc);
    acc = fmaf(fmaxf(x.y, 0.0f), Ws[(k4 * 4 + 1) * 64 + f], acc);
    acc = fmaf(fmaxf(x.z, 0.0f), Ws[(k4 * 4 + 2) * 64 + f], acc);
    acc = fmaf(fmaxf(x.w, 0.0f), Ws[(k4 * 4 + 3) * 64 + f], acc);
  }
  h[(long)node * 64 + f] = (_Float16)acc;
}

// ---------- pull-gather: one wave per dst node ----------
// lane = eg*16 + fl: 16 lanes cover 64 features (float4 each), 4 edge-groups in flight.
// MODE 0: out[node*64 + f] = b[f] + aggregate (fp32 row)
// MODE 1: out[node] = sigmoid( relu(b + aggregate) . Wl + bl )
template <int MODE>
__global__ __launch_bounds__(256) void k_gather(const _Float16* __restrict__ h,
                                                const float* __restrict__ dis,
                                                const float2* __restrict__ edges,
                                                const int* __restrict__ rowptr,
                                                const float* __restrict__ b,
                                                const float* __restrict__ Wl,
                                                const float* __restrict__ bl,
                                                float* __restrict__ out, int n) {
  int lane = threadIdx.x & 63;
  int fl = lane & 15;   // feature group (features fl*4 .. fl*4+3)
  int eg = lane >> 4;   // edge group
  int node = blockIdx.x * 4 + (threadIdx.x >> 6);
  if (node >= n) return;
  int beg = rowptr[node], end = rowptr[node + 1];
  float s0 = dis[node];
  float4 acc = make_float4(0.0f, 0.0f, 0.0f, 0.0f);

  for (int base = beg; base < end; base += 64) {
    int m = end - base; if (m > 64) m = 64;
    // stage up to 64 edges across lanes; invalid lanes get (src=0, w=0) -> nrm=0
    float2 pk = (lane < m) ? edges[base + lane] : make_float2(__int_as_float(0), 0.0f);
    float nrm = dis[__float_as_int(pk.x)] * pk.y * s0;
    int steps = (m + 3) >> 2;
    for (int s = 0; s < steps; ++s) {
      int j = s * 4 + eg;
      int   sj = __float_as_int(__shfl(pk.x, j));
      float nj = __shfl(nrm, j);
      half4 hv = *(const half4*)(h + (size_t)sj * 64 + fl * 4);
      acc.x = fmaf((float)hv.x, nj, acc.x);
      acc.y = fmaf((float)hv.y, nj, acc.y);
      acc.z = fmaf((float)hv.z, nj, acc.z);
      acc.w = fmaf((float)hv.w, nj, acc.w);
    }
  }
  // reduce across the 4 edge groups (lanes fl, fl+16, fl+32, fl+48)
#pragma unroll
  for (int off = 16; off < 64; off <<= 1) {
    acc.x += __shfl_xor(acc.x, off);
    acc.y += __shfl_xor(acc.y, off);
    acc.z += __shfl_xor(acc.z, off);
    acc.w += __shfl_xor(acc.w, off);
  }
  // bias + self-loop message
  half4 hs = *(const half4*)(h + (size_t)node * 64 + fl * 4);
  float4 bv = *(const float4*)(b + fl * 4);
  float s2 = s0 * s0;
  acc.x += bv.x + (float)hs.x * s2;
  acc.y += bv.y + (float)hs.y * s2;
  acc.z += bv.z + (float)hs.z * s2;
  acc.w += bv.w + (float)hs.w * s2;

  if (MODE == 0) {
    if (eg == 0) *(float4*)(out + (size_t)node * 64 + fl * 4) = acc;
  } else {
    float4 wl = *(const float4*)(Wl + fl * 4);
    float v = fmaxf(acc.x, 0.0f) * wl.x + fmaxf(acc.y, 0.0f) * wl.y +
              fmaxf(acc.z, 0.0f) * wl.z + fmaxf(acc.w, 0.0f) * wl.w;
#pragma unroll
    for (int off = 1; off < 16; off <<= 1) v += __shfl_xor(v, off);
    if (lane == 0) out[node] = 1.0f / (1.0f + expf(-(v + bl[0])));
  }
}

extern "C" void kernel_launch(void* const* d_in, const int* in_sizes, int n_in,
                              void* d_out, int out_size, void* d_ws, size_t ws_size,
                              hipStream_t stream) {
  const float* X  = (const float*)d_in[0];
  const void*  EI = d_in[1];
  const float* EW = (const float*)d_in[2];
  const float* W1 = (const float*)d_in[3];
  const float* b1 = (const float*)d_in[4];
  const float* W2 = (const float*)d_in[5];
  const float* b2 = (const float*)d_in[6];
  const float* Wl = (const float*)d_in[7];
  const float* bl = (const float*)d_in[8];
  float* out = (float*)d_out;

  const int  n = in_sizes[0] / 128;      // 50000
  const long E = (long)in_sizes[1] / 2;  // 1,600,000

  auto align = [](size_t x) { return (x + 255) & ~(size_t)255; };
  char* ws = (char*)d_ws;
  size_t off = 0;
  int*            flag   = (int*)(ws + off);            off += 256;
  float*          dis    = (float*)(ws + off);          off += align((size_t)n * 4);
  int*            count  = (int*)(ws + off);            off += align((size_t)n * 4);
  int*            rowptr = (int*)(ws + off);            off += align((size_t)(n + 1) * 4);
  int*            bsum   = (int*)(ws + off);            off += 256;
  unsigned short* slot   = (unsigned short*)(ws + off); off += align((size_t)E * 2);
  float2*         edges  = (float2*)(ws + off);         off += align((size_t)E * 8);
  _Float16*       A      = (_Float16*)(ws + off);       off += align((size_t)n * 64 * 2);
  float*          B      = (float*)(ws + off);          off += align((size_t)n * 64 * 4);

  dim3 blk(256);
  const int nbN = (n + 255) / 256;
  const int nbE2 = (int)((E / 2 + 255) / 256);  // 2 edges per thread
  const int nb  = (n + 1023) / 1024;            // scan chunks (<=64)
  const int nbW = (n + 3) / 4;                  // 4 waves/block kernels

  k_detect<<<1, 256, 0, stream>>>((const unsigned long long*)EI, flag);
  k_zero<<<nbN, blk, 0, stream>>>(count, n);
  k_hist<<<nbE2, blk, 0, stream>>>(EI, flag, count, slot, E);

  // CSR build
  k_scansum<<<nb, blk, 0, stream>>>(count, bsum, n);
  k_scanoffsets<<<1, 64, 0, stream>>>(bsum, rowptr, nb, n);
  k_scanwrite<<<nb, blk, 0, stream>>>(count, bsum, rowptr, n);
  k_permute<<<nbE2, blk, 0, stream>>>(EI, flag, EW, rowptr, slot, edges, E);

  // degree + rsqrt from CSR rows
  k_deg_rsqrt<<<nbW, blk, 0, stream>>>(edges, rowptr, dis, n);

  // layer 1
  k_gemm1<<<nbW, blk, 0, stream>>>(X, W1, A, n);
  k_gather<0><<<nbW, blk, 0, stream>>>(A, dis, edges, rowptr, b1, Wl, bl, B, n);

  // layer 2 (relu fused into gemm2 read; readout fused into gather epilogue)
  k_gemm2<<<nbW, blk, 0, stream>>>(B, W2, A, n);
  k_gather<1><<<nbW, blk, 0, stream>>>(A, dis, edges, rowptr, b2, Wl, bl, out, n);
}

// Round 5
// 364.101 us; speedup vs baseline: 2.9774x; 1.0530x over previous
//
#include <hip/hip_runtime.h>

typedef _Float16 half8 __attribute__((ext_vector_type(8)));

// ---------- helpers ----------
__device__ __forceinline__ long ld_idx(const void* idx, long pos, int is64) {
  return is64 ? (long)((const long long*)idx)[pos]
              : (long)((const int*)idx)[pos];
}

// Detect whether edge_index is int64 (flag=1) or int32 (flag=0).
__global__ void k_detect(const unsigned long long* __restrict__ p, int* __restrict__ flag) {
  if (threadIdx.x == 0) *flag = 1;
  __syncthreads();
  if (p[threadIdx.x] >= (1ULL << 32)) atomicExch(flag, 0);
}

__global__ void k_zero(int* __restrict__ p, long n) {
  long i = (long)blockIdx.x * blockDim.x + threadIdx.x;
  if (i < n) p[i] = 0;
}

// in-degree histogram at dst; slot[e] = position of edge e within its dst row
__global__ void k_hist(const void* __restrict__ idx, const int* __restrict__ flag,
                       int* __restrict__ count, unsigned short* __restrict__ slot, long E) {
  long e = 2 * ((long)blockIdx.x * blockDim.x + threadIdx.x);
  if (e >= E) return;
  int is64 = *flag;
  long d0, d1 = -1;
  if (is64) {
    const longlong2 dd = *(const longlong2*)((const long long*)idx + E + e);
    d0 = dd.x; d1 = dd.y;
  } else {
    const int2 dd = *(const int2*)((const int*)idx + E + e);
    d0 = dd.x; d1 = dd.y;
  }
  unsigned short s0 = (unsigned short)atomicAdd(&count[d0], 1);
  unsigned short s1 = 0;
  if (e + 1 < E) s1 = (unsigned short)atomicAdd(&count[d1], 1);
  *(ushort2*)(slot + e) = make_ushort2(s0, s1);
}

// ---------- scan (exclusive prefix sum of count -> rowptr) ----------
__global__ __launch_bounds__(256) void k_scansum(const int* __restrict__ count, int* __restrict__ bsum, int n) {
  __shared__ int sh[256];
  int t = threadIdx.x;
  int base = blockIdx.x * 1024 + t * 4;
  int s = 0;
#pragma unroll
  for (int k = 0; k < 4; ++k) { int i = base + k; if (i < n) s += count[i]; }
  sh[t] = s; __syncthreads();
  for (int off = 128; off > 0; off >>= 1) {
    if (t < off) sh[t] += sh[t + off];
    __syncthreads();
  }
  if (t == 0) bsum[blockIdx.x] = sh[0];
}

__global__ void k_scanoffsets(int* __restrict__ bsum, int* __restrict__ rowptr, int nb, int n) {
  int t = threadIdx.x;  // 64 threads
  int v = (t < nb) ? bsum[t] : 0;
  int inc = v;
#pragma unroll
  for (int off = 1; off < 64; off <<= 1) {
    int u = __shfl_up(inc, off);
    if (t >= off) inc += u;
  }
  if (t < nb) bsum[t] = inc - v;      // exclusive
  if (t == nb - 1) rowptr[n] = inc;   // total = E
}

__global__ __launch_bounds__(256) void k_scanwrite(const int* __restrict__ count,
                                                   const int* __restrict__ bsum,
                                                   int* __restrict__ rowptr, int n) {
  __shared__ int sh[256];
  int t = threadIdx.x;
  int base = blockIdx.x * 1024 + t * 4;
  int c[4]; int s = 0;
#pragma unroll
  for (int k = 0; k < 4; ++k) { int i = base + k; c[k] = (i < n) ? count[i] : 0; s += c[k]; }
  sh[t] = s; __syncthreads();
  for (int off = 1; off < 256; off <<= 1) {
    int u = (t >= off) ? sh[t - off] : 0;
    __syncthreads();
    sh[t] += u;
    __syncthreads();
  }
  int excl = sh[t] - s + bsum[blockIdx.x];
#pragma unroll
  for (int k = 0; k < 4; ++k) {
    int i = base + k;
    if (i < n) rowptr[i] = excl;
    excl += c[k];
  }
}

// ---------- permute edges into CSR-by-dst (atomic-free), payload = (src, w) ----------
__global__ void k_permute(const void* __restrict__ idx, const int* __restrict__ flag,
                          const float* __restrict__ w, const int* __restrict__ rowptr,
                          const unsigned short* __restrict__ slot,
                          float2* __restrict__ edges, long E) {
  long e = 2 * ((long)blockIdx.x * blockDim.x + threadIdx.x);
  if (e >= E) return;
  int is64 = *flag;
  long s0, s1 = 0, d0, d1 = 0;
  if (is64) {
    const longlong2 ss = *(const longlong2*)((const long long*)idx + e);
    const longlong2 dd = *(const longlong2*)((const long long*)idx + E + e);
    s0 = ss.x; s1 = ss.y; d0 = dd.x; d1 = dd.y;
  } else {
    const int2 ss = *(const int2*)((const int*)idx + e);
    const int2 dd = *(const int2*)((const int*)idx + E + e);
    s0 = ss.x; s1 = ss.y; d0 = dd.x; d1 = dd.y;
  }
  const ushort2 sl = *(const ushort2*)(slot + e);
  const float2 wv = *(const float2*)(w + e);
  edges[rowptr[d0] + (int)sl.x] = make_float2(__int_as_float((int)s0), wv.x);
  if (e + 1 < E)
    edges[rowptr[d1] + (int)sl.y] = make_float2(__int_as_float((int)s1), wv.y);
}

// ---------- weighted degree from CSR rows + fused rsqrt: dis[i] = rsqrt(1 + sum w) ----------
__global__ __launch_bounds__(256) void k_deg_rsqrt(const float2* __restrict__ edges,
                                                   const int* __restrict__ rowptr,
                                                   float* __restrict__ dis, int n) {
  int lane = threadIdx.x & 63;
  int node = blockIdx.x * 4 + (threadIdx.x >> 6);
  if (node >= n) return;
  int beg = rowptr[node], end = rowptr[node + 1];
  float s = 0.0f;
  for (int i = beg + lane; i < end; i += 64) s += edges[i].y;
#pragma unroll
  for (int off = 32; off > 0; off >>= 1) s += __shfl_down(s, off);
  if (lane == 0) dis[node] = rsqrtf(1.0f + s);   // deg >= 1 always (self-loop)
}

// ---------- dense layers: persistent waves, W column in registers, uniform X reads ----------
// h[n,64] = X[n,128] @ W[128,64], store fp16
__global__ __launch_bounds__(256) void k_gemm1(const float* __restrict__ X,
                                               const float* __restrict__ W,
                                               _Float16* __restrict__ h, int n) {
  int f = threadIdx.x & 63;
  float wr[128];
#pragma unroll
  for (int k = 0; k < 128; ++k) wr[k] = W[k * 64 + f];   // coalesced; lane f = column f
  int wave = __builtin_amdgcn_readfirstlane(blockIdx.x * 4 + (threadIdx.x >> 6));
  int nw = gridDim.x * 4;
  for (int node = wave; node < n; node += nw) {
    const float4* xr = (const float4*)(X + (size_t)node * 128);  // wave-uniform -> s_load
    float acc = 0.0f;
#pragma unroll
    for (int k4 = 0; k4 < 32; ++k4) {
      float4 x = xr[k4];
      acc = fmaf(x.x, wr[k4 * 4 + 0], acc);
      acc = fmaf(x.y, wr[k4 * 4 + 1], acc);
      acc = fmaf(x.z, wr[k4 * 4 + 2], acc);
      acc = fmaf(x.w, wr[k4 * 4 + 3], acc);
    }
    h[(size_t)node * 64 + f] = (_Float16)acc;
  }
}

// h[n,64] = relu(in[n,64]) @ W[64,64], store fp16
__global__ __launch_bounds__(256) void k_gemm2(const float* __restrict__ in,
                                               const float* __restrict__ W,
                                               _Float16* __restrict__ h, int n) {
  int f = threadIdx.x & 63;
  float wr[64];
#pragma unroll
  for (int k = 0; k < 64; ++k) wr[k] = W[k * 64 + f];
  int wave = __builtin_amdgcn_readfirstlane(blockIdx.x * 4 + (threadIdx.x >> 6));
  int nw = gridDim.x * 4;
  for (int node = wave; node < n; node += nw) {
    const float4* xr = (const float4*)(in + (size_t)node * 64);  // wave-uniform -> s_load
    float acc = 0.0f;
#pragma unroll
    for (int k4 = 0; k4 < 16; ++k4) {
      float4 x = xr[k4];
      acc = fmaf(fmaxf(x.x, 0.0f), wr[k4 * 4 + 0], acc);
      acc = fmaf(fmaxf(x.y, 0.0f), wr[k4 * 4 + 1], acc);
      acc = fmaf(fmaxf(x.z, 0.0f), wr[k4 * 4 + 2], acc);
      acc = fmaf(fmaxf(x.w, 0.0f), wr[k4 * 4 + 3], acc);
    }
    h[(size_t)node * 64 + f] = (_Float16)acc;
  }
}

// ---------- pull-gather: one wave per dst node ----------
// lane = eg*8 + fl: 8 lanes cover 64 features (half8 = 16B each), 8 edge-groups in flight.
// MODE 0: out[node*64 + f] = b[f] + aggregate (fp32 row)
// MODE 1: out[node] = sigmoid( relu(b + aggregate) . Wl + bl )
template <int MODE>
__global__ __launch_bounds__(256) void k_gather(const _Float16* __restrict__ h,
                                                const float* __restrict__ dis,
                                                const float2* __restrict__ edges,
                                                const int* __restrict__ rowptr,
                                                const float* __restrict__ b,
                                                const float* __restrict__ Wl,
                                                const float* __restrict__ bl,
                                                float* __restrict__ out, int n) {
  int lane = threadIdx.x & 63;
  int fl = lane & 7;    // feature group (features fl*8 .. fl*8+7)
  int eg = lane >> 3;   // edge group 0..7
  int node = blockIdx.x * 4 + (threadIdx.x >> 6);
  if (node >= n) return;
  int beg = rowptr[node], end = rowptr[node + 1];
  float s0 = dis[node];
  float acc[8];
#pragma unroll
  for (int i = 0; i < 8; ++i) acc[i] = 0.0f;

  for (int base = beg; base < end; base += 64) {
    int m = end - base; if (m > 64) m = 64;
    // stage up to 64 edges across lanes; invalid lanes get (src=0, w=0) -> nrm=0
    float2 pk = (lane < m) ? edges[base + lane] : make_float2(__int_as_float(0), 0.0f);
    float nrm = dis[__float_as_int(pk.x)] * pk.y * s0;
    int steps = (m + 7) >> 3;
    for (int s = 0; s < steps; ++s) {
      int j = s * 8 + eg;
      int   sj = __float_as_int(__shfl(pk.x, j));
      float nj = __shfl(nrm, j);
      half8 hv = *(const half8*)(h + (size_t)sj * 64 + fl * 8);
#pragma unroll
      for (int i = 0; i < 8; ++i) acc[i] = fmaf((float)hv[i], nj, acc[i]);
    }
  }
  // reduce across the 8 edge groups (lanes fl, fl+8, ..., fl+56)
#pragma unroll
  for (int off = 8; off < 64; off <<= 1)
#pragma unroll
    for (int i = 0; i < 8; ++i) acc[i] += __shfl_xor(acc[i], off);

  // bias + self-loop message
  half8 hs = *(const half8*)(h + (size_t)node * 64 + fl * 8);
  float4 bv0 = *(const float4*)(b + fl * 8);
  float4 bv1 = *(const float4*)(b + fl * 8 + 4);
  float bb[8] = {bv0.x, bv0.y, bv0.z, bv0.w, bv1.x, bv1.y, bv1.z, bv1.w};
  float s2 = s0 * s0;
#pragma unroll
  for (int i = 0; i < 8; ++i) acc[i] += bb[i] + (float)hs[i] * s2;

  if (MODE == 0) {
    if (eg == 0) {
      float4 o0 = make_float4(acc[0], acc[1], acc[2], acc[3]);
      float4 o1 = make_float4(acc[4], acc[5], acc[6], acc[7]);
      *(float4*)(out + (size_t)node * 64 + fl * 8) = o0;
      *(float4*)(out + (size_t)node * 64 + fl * 8 + 4) = o1;
    }
  } else {
    float4 wl0 = *(const float4*)(Wl + fl * 8);
    float4 wl1 = *(const float4*)(Wl + fl * 8 + 4);
    float wl[8] = {wl0.x, wl0.y, wl0.z, wl0.w, wl1.x, wl1.y, wl1.z, wl1.w};
    float v = 0.0f;
#pragma unroll
    for (int i = 0; i < 8; ++i) v += fmaxf(acc[i], 0.0f) * wl[i];
#pragma unroll
    for (int off = 1; off < 8; off <<= 1) v += __shfl_xor(v, off);
    if (lane == 0) out[node] = 1.0f / (1.0f + expf(-(v + bl[0])));
  }
}

extern "C" void kernel_launch(void* const* d_in, const int* in_sizes, int n_in,
                              void* d_out, int out_size, void* d_ws, size_t ws_size,
                              hipStream_t stream) {
  const float* X  = (const float*)d_in[0];
  const void*  EI = d_in[1];
  const float* EW = (const float*)d_in[2];
  const float* W1 = (const float*)d_in[3];
  const float* b1 = (const float*)d_in[4];
  const float* W2 = (const float*)d_in[5];
  const float* b2 = (const float*)d_in[6];
  const float* Wl = (const float*)d_in[7];
  const float* bl = (const float*)d_in[8];
  float* out = (float*)d_out;

  const int  n = in_sizes[0] / 128;      // 50000
  const long E = (long)in_sizes[1] / 2;  // 1,600,000

  auto align = [](size_t x) { return (x + 255) & ~(size_t)255; };
  char* ws = (char*)d_ws;
  size_t off = 0;
  int*            flag   = (int*)(ws + off);            off += 256;
  float*          dis    = (float*)(ws + off);          off += align((size_t)n * 4);
  int*            count  = (int*)(ws + off);            off += align((size_t)n * 4);
  int*            rowptr = (int*)(ws + off);            off += align((size_t)(n + 1) * 4);
  int*            bsum   = (int*)(ws + off);            off += 256;
  unsigned short* slot   = (unsigned short*)(ws + off); off += align((size_t)E * 2);
  float2*         edges  = (float2*)(ws + off);         off += align((size_t)E * 8);
  _Float16*       A      = (_Float16*)(ws + off);       off += align((size_t)n * 64 * 2);
  float*          B      = (float*)(ws + off);          off += align((size_t)n * 64 * 4);

  dim3 blk(256);
  const int nbN = (n + 255) / 256;
  const int nbE2 = (int)((E / 2 + 255) / 256);  // 2 edges per thread
  const int nb  = (n + 1023) / 1024;            // scan chunks (<=64)
  const int nbW = (n + 3) / 4;                  // 4 waves/block kernels

  k_detect<<<1, 256, 0, stream>>>((const unsigned long long*)EI, flag);
  k_zero<<<nbN, blk, 0, stream>>>(count, n);
  k_hist<<<nbE2, blk, 0, stream>>>(EI, flag, count, slot, E);

  // CSR build
  k_scansum<<<nb, blk, 0, stream>>>(count, bsum, n);
  k_scanoffsets<<<1, 64, 0, stream>>>(bsum, rowptr, nb, n);
  k_scanwrite<<<nb, blk, 0, stream>>>(count, bsum, rowptr, n);
  k_permute<<<nbE2, blk, 0, stream>>>(EI, flag, EW, rowptr, slot, edges, E);

  // degree + rsqrt from CSR rows
  k_deg_rsqrt<<<nbW, blk, 0, stream>>>(edges, rowptr, dis, n);

  // layer 1 (persistent GEMM: 512 blocks)
  k_gemm1<<<512, blk, 0, stream>>>(X, W1, A, n);
  k_gather<0><<<nbW, blk, 0, stream>>>(A, dis, edges, rowptr, b1, Wl, bl, B, n);

  // layer 2 (relu fused into gemm2 read; readout fused into gather epilogue)
  k_gemm2<<<512, blk, 0, stream>>>(B, W2, A, n);
  k_gather<1><<<nbW, blk, 0, stream>>>(A, dis, edges, rowptr, b2, Wl, bl, out, n);
}

// Round 6
// 324.918 us; speedup vs baseline: 3.3364x; 1.1206x over previous
//
#include <hip/hip_runtime.h>

typedef _Float16 half8 __attribute__((ext_vector_type(8)));

// ---------- helpers ----------
__device__ __forceinline__ long ld_idx(const void* idx, long pos, int is64) {
  return is64 ? (long)((const long long*)idx)[pos]
              : (long)((const int*)idx)[pos];
}

// Detect whether edge_index is int64 (flag=1) or int32 (flag=0).
__global__ void k_detect(const unsigned long long* __restrict__ p, int* __restrict__ flag) {
  if (threadIdx.x == 0) *flag = 1;
  __syncthreads();
  if (p[threadIdx.x] >= (1ULL << 32)) atomicExch(flag, 0);
}

__global__ void k_zero(int* __restrict__ p, long n) {
  long i = (long)blockIdx.x * blockDim.x + threadIdx.x;
  if (i < n) p[i] = 0;
}

// in-degree histogram at dst; slot[e] = position of edge e within its dst row
__global__ void k_hist(const void* __restrict__ idx, const int* __restrict__ flag,
                       int* __restrict__ count, unsigned short* __restrict__ slot, long E) {
  long e = 2 * ((long)blockIdx.x * blockDim.x + threadIdx.x);
  if (e >= E) return;
  int is64 = *flag;
  long d0, d1 = -1;
  if (is64) {
    const longlong2 dd = *(const longlong2*)((const long long*)idx + E + e);
    d0 = dd.x; d1 = dd.y;
  } else {
    const int2 dd = *(const int2*)((const int*)idx + E + e);
    d0 = dd.x; d1 = dd.y;
  }
  unsigned short s0 = (unsigned short)atomicAdd(&count[d0], 1);
  unsigned short s1 = 0;
  if (e + 1 < E) s1 = (unsigned short)atomicAdd(&count[d1], 1);
  *(ushort2*)(slot + e) = make_ushort2(s0, s1);
}

// ---------- scan (exclusive prefix sum of count -> rowptr) ----------
__global__ __launch_bounds__(256) void k_scansum(const int* __restrict__ count, int* __restrict__ bsum, int n) {
  __shared__ int sh[256];
  int t = threadIdx.x;
  int base = blockIdx.x * 1024 + t * 4;
  int s = 0;
#pragma unroll
  for (int k = 0; k < 4; ++k) { int i = base + k; if (i < n) s += count[i]; }
  sh[t] = s; __syncthreads();
  for (int off = 128; off > 0; off >>= 1) {
    if (t < off) sh[t] += sh[t + off];
    __syncthreads();
  }
  if (t == 0) bsum[blockIdx.x] = sh[0];
}

__global__ void k_scanoffsets(int* __restrict__ bsum, int* __restrict__ rowptr, int nb, int n) {
  int t = threadIdx.x;  // 64 threads
  int v = (t < nb) ? bsum[t] : 0;
  int inc = v;
#pragma unroll
  for (int off = 1; off < 64; off <<= 1) {
    int u = __shfl_up(inc, off);
    if (t >= off) inc += u;
  }
  if (t < nb) bsum[t] = inc - v;      // exclusive
  if (t == nb - 1) rowptr[n] = inc;   // total = E
}

__global__ __launch_bounds__(256) void k_scanwrite(const int* __restrict__ count,
                                                   const int* __restrict__ bsum,
                                                   int* __restrict__ rowptr, int n) {
  __shared__ int sh[256];
  int t = threadIdx.x;
  int base = blockIdx.x * 1024 + t * 4;
  int c[4]; int s = 0;
#pragma unroll
  for (int k = 0; k < 4; ++k) { int i = base + k; c[k] = (i < n) ? count[i] : 0; s += c[k]; }
  sh[t] = s; __syncthreads();
  for (int off = 1; off < 256; off <<= 1) {
    int u = (t >= off) ? sh[t - off] : 0;
    __syncthreads();
    sh[t] += u;
    __syncthreads();
  }
  int excl = sh[t] - s + bsum[blockIdx.x];
#pragma unroll
  for (int k = 0; k < 4; ++k) {
    int i = base + k;
    if (i < n) rowptr[i] = excl;
    excl += c[k];
  }
}

// ---------- permute edges into CSR-by-dst (atomic-free), payload = (src, w) ----------
__global__ void k_permute(const void* __restrict__ idx, const int* __restrict__ flag,
                          const float* __restrict__ w, const int* __restrict__ rowptr,
                          const unsigned short* __restrict__ slot,
                          float2* __restrict__ edges, long E) {
  long e = 2 * ((long)blockIdx.x * blockDim.x + threadIdx.x);
  if (e >= E) return;
  int is64 = *flag;
  long s0, s1 = 0, d0, d1 = 0;
  if (is64) {
    const longlong2 ss = *(const longlong2*)((const long long*)idx + e);
    const longlong2 dd = *(const longlong2*)((const long long*)idx + E + e);
    s0 = ss.x; s1 = ss.y; d0 = dd.x; d1 = dd.y;
  } else {
    const int2 ss = *(const int2*)((const int*)idx + e);
    const int2 dd = *(const int2*)((const int*)idx + E + e);
    s0 = ss.x; s1 = ss.y; d0 = dd.x; d1 = dd.y;
  }
  const ushort2 sl = *(const ushort2*)(slot + e);
  const float2 wv = *(const float2*)(w + e);
  edges[rowptr[d0] + (int)sl.x] = make_float2(__int_as_float((int)s0), wv.x);
  if (e + 1 < E)
    edges[rowptr[d1] + (int)sl.y] = make_float2(__int_as_float((int)s1), wv.y);
}

// ---------- weighted degree from CSR rows + fused rsqrt: dis[i] = rsqrt(1 + sum w) ----------
__global__ __launch_bounds__(256) void k_deg_rsqrt(const float2* __restrict__ edges,
                                                   const int* __restrict__ rowptr,
                                                   float* __restrict__ dis, int n) {
  int lane = threadIdx.x & 63;
  int node = blockIdx.x * 4 + (threadIdx.x >> 6);
  if (node >= n) return;
  int beg = rowptr[node], end = rowptr[node + 1];
  float s = 0.0f;
  for (int i = beg + lane; i < end; i += 64) s += edges[i].y;
#pragma unroll
  for (int off = 32; off > 0; off >>= 1) s += __shfl_down(s, off);
  if (lane == 0) dis[node] = rsqrtf(1.0f + s);   // deg >= 1 always (self-loop)
}

// ---------- dense layers: thread = node, 64 accumulators, W broadcast from LDS ----------
// h[n,64] = X[n,128] @ W[128,64], store fp16
__global__ __launch_bounds__(128) void k_gemm1(const float* __restrict__ X,
                                               const float* __restrict__ W,
                                               _Float16* __restrict__ h, int n) {
  __shared__ float Ws[128 * 64];
  for (int i = threadIdx.x; i < 2048; i += 128)
    ((float4*)Ws)[i] = ((const float4*)W)[i];
  __syncthreads();
  int node = blockIdx.x * 128 + threadIdx.x;
  if (node >= n) return;
  const float4* xr4 = (const float4*)(X + (size_t)node * 128);
  float acc[64];
#pragma unroll
  for (int f = 0; f < 64; ++f) acc[f] = 0.0f;
  for (int k4 = 0; k4 < 32; ++k4) {
    float4 x = xr4[k4];
#pragma unroll
    for (int kk = 0; kk < 4; ++kk) {
      float xv = (kk == 0) ? x.x : (kk == 1) ? x.y : (kk == 2) ? x.z : x.w;
      const float4* wrow = (const float4*)(Ws + (k4 * 4 + kk) * 64);
#pragma unroll
      for (int f4 = 0; f4 < 16; ++f4) {
        float4 w = wrow[f4];
        acc[f4 * 4 + 0] = fmaf(xv, w.x, acc[f4 * 4 + 0]);
        acc[f4 * 4 + 1] = fmaf(xv, w.y, acc[f4 * 4 + 1]);
        acc[f4 * 4 + 2] = fmaf(xv, w.z, acc[f4 * 4 + 2]);
        acc[f4 * 4 + 3] = fmaf(xv, w.w, acc[f4 * 4 + 3]);
      }
    }
  }
  _Float16* hp = h + (size_t)node * 64;
#pragma unroll
  for (int g = 0; g < 8; ++g) {
    half8 o;
#pragma unroll
    for (int i = 0; i < 8; ++i) o[i] = (_Float16)acc[g * 8 + i];
    *(half8*)(hp + g * 8) = o;
  }
}

// h[n,64] = relu(in[n,64]) @ W[64,64], store fp16
__global__ __launch_bounds__(128) void k_gemm2(const float* __restrict__ in,
                                               const float* __restrict__ W,
                                               _Float16* __restrict__ h, int n) {
  __shared__ float Ws[64 * 64];
  for (int i = threadIdx.x; i < 1024; i += 128)
    ((float4*)Ws)[i] = ((const float4*)W)[i];
  __syncthreads();
  int node = blockIdx.x * 128 + threadIdx.x;
  if (node >= n) return;
  const float4* xr4 = (const float4*)(in + (size_t)node * 64);
  float acc[64];
#pragma unroll
  for (int f = 0; f < 64; ++f) acc[f] = 0.0f;
  for (int k4 = 0; k4 < 16; ++k4) {
    float4 x = xr4[k4];
#pragma unroll
    for (int kk = 0; kk < 4; ++kk) {
      float xv = (kk == 0) ? x.x : (kk == 1) ? x.y : (kk == 2) ? x.z : x.w;
      xv = fmaxf(xv, 0.0f);  // relu fused
      const float4* wrow = (const float4*)(Ws + (k4 * 4 + kk) * 64);
#pragma unroll
      for (int f4 = 0; f4 < 16; ++f4) {
        float4 w = wrow[f4];
        acc[f4 * 4 + 0] = fmaf(xv, w.x, acc[f4 * 4 + 0]);
        acc[f4 * 4 + 1] = fmaf(xv, w.y, acc[f4 * 4 + 1]);
        acc[f4 * 4 + 2] = fmaf(xv, w.z, acc[f4 * 4 + 2]);
        acc[f4 * 4 + 3] = fmaf(xv, w.w, acc[f4 * 4 + 3]);
      }
    }
  }
  _Float16* hp = h + (size_t)node * 64;
#pragma unroll
  for (int g = 0; g < 8; ++g) {
    half8 o;
#pragma unroll
    for (int i = 0; i < 8; ++i) o[i] = (_Float16)acc[g * 8 + i];
    *(half8*)(hp + g * 8) = o;
  }
}

// ---------- pull-gather: one wave per dst node ----------
// lane = eg*8 + fl: 8 lanes cover 64 features (half8 = 16B each), 8 edge-groups in flight.
// MODE 0: out[node*64 + f] = b[f] + aggregate (fp32 row)
// MODE 1: out[node] = sigmoid( relu(b + aggregate) . Wl + bl )
template <int MODE>
__global__ __launch_bounds__(256) void k_gather(const _Float16* __restrict__ h,
                                                const float* __restrict__ dis,
                                                const float2* __restrict__ edges,
                                                const int* __restrict__ rowptr,
                                                const float* __restrict__ b,
                                                const float* __restrict__ Wl,
                                                const float* __restrict__ bl,
                                                float* __restrict__ out, int n) {
  int lane = threadIdx.x & 63;
  int fl = lane & 7;    // feature group (features fl*8 .. fl*8+7)
  int eg = lane >> 3;   // edge group 0..7
  int node = blockIdx.x * 4 + (threadIdx.x >> 6);
  if (node >= n) return;
  int beg = rowptr[node], end = rowptr[node + 1];
  float s0 = dis[node];
  float acc[8];
#pragma unroll
  for (int i = 0; i < 8; ++i) acc[i] = 0.0f;

  for (int base = beg; base < end; base += 64) {
    int m = end - base; if (m > 64) m = 64;
    // stage up to 64 edges across lanes; invalid lanes get (src=0, w=0) -> nrm=0
    float2 pk = (lane < m) ? edges[base + lane] : make_float2(__int_as_float(0), 0.0f);
    float nrm = dis[__float_as_int(pk.x)] * pk.y * s0;
    int steps = (m + 7) >> 3;
    for (int s = 0; s < steps; ++s) {
      int j = s * 8 + eg;
      int   sj = __float_as_int(__shfl(pk.x, j));
      float nj = __shfl(nrm, j);
      half8 hv = *(const half8*)(h + (size_t)sj * 64 + fl * 8);
#pragma unroll
      for (int i = 0; i < 8; ++i) acc[i] = fmaf((float)hv[i], nj, acc[i]);
    }
  }
  // reduce across the 8 edge groups (lanes fl, fl+8, ..., fl+56)
#pragma unroll
  for (int off = 8; off < 64; off <<= 1)
#pragma unroll
    for (int i = 0; i < 8; ++i) acc[i] += __shfl_xor(acc[i], off);

  // bias + self-loop message
  half8 hs = *(const half8*)(h + (size_t)node * 64 + fl * 8);
  float4 bv0 = *(const float4*)(b + fl * 8);
  float4 bv1 = *(const float4*)(b + fl * 8 + 4);
  float bb[8] = {bv0.x, bv0.y, bv0.z, bv0.w, bv1.x, bv1.y, bv1.z, bv1.w};
  float s2 = s0 * s0;
#pragma unroll
  for (int i = 0; i < 8; ++i) acc[i] += bb[i] + (float)hs[i] * s2;

  if (MODE == 0) {
    if (eg == 0) {
      float4 o0 = make_float4(acc[0], acc[1], acc[2], acc[3]);
      float4 o1 = make_float4(acc[4], acc[5], acc[6], acc[7]);
      *(float4*)(out + (size_t)node * 64 + fl * 8) = o0;
      *(float4*)(out + (size_t)node * 64 + fl * 8 + 4) = o1;
    }
  } else {
    float4 wl0 = *(const float4*)(Wl + fl * 8);
    float4 wl1 = *(const float4*)(Wl + fl * 8 + 4);
    float wl[8] = {wl0.x, wl0.y, wl0.z, wl0.w, wl1.x, wl1.y, wl1.z, wl1.w};
    float v = 0.0f;
#pragma unroll
    for (int i = 0; i < 8; ++i) v += fmaxf(acc[i], 0.0f) * wl[i];
#pragma unroll
    for (int off = 1; off < 8; off <<= 1) v += __shfl_xor(v, off);
    if (lane == 0) out[node] = 1.0f / (1.0f + expf(-(v + bl[0])));
  }
}

extern "C" void kernel_launch(void* const* d_in, const int* in_sizes, int n_in,
                              void* d_out, int out_size, void* d_ws, size_t ws_size,
                              hipStream_t stream) {
  const float* X  = (const float*)d_in[0];
  const void*  EI = d_in[1];
  const float* EW = (const float*)d_in[2];
  const float* W1 = (const float*)d_in[3];
  const float* b1 = (const float*)d_in[4];
  const float* W2 = (const float*)d_in[5];
  const float* b2 = (const float*)d_in[6];
  const float* Wl = (const float*)d_in[7];
  const float* bl = (const float*)d_in[8];
  float* out = (float*)d_out;

  const int  n = in_sizes[0] / 128;      // 50000
  const long E = (long)in_sizes[1] / 2;  // 1,600,000

  auto align = [](size_t x) { return (x + 255) & ~(size_t)255; };
  char* ws = (char*)d_ws;
  size_t off = 0;
  int*            flag   = (int*)(ws + off);            off += 256;
  float*          dis    = (float*)(ws + off);          off += align((size_t)n * 4);
  int*            count  = (int*)(ws + off);            off += align((size_t)n * 4);
  int*            rowptr = (int*)(ws + off);            off += align((size_t)(n + 1) * 4);
  int*            bsum   = (int*)(ws + off);            off += 256;
  unsigned short* slot   = (unsigned short*)(ws + off); off += align((size_t)E * 2);
  float2*         edges  = (float2*)(ws + off);         off += align((size_t)E * 8);
  _Float16*       A      = (_Float16*)(ws + off);       off += align((size_t)n * 64 * 2);
  float*          B      = (float*)(ws + off);          off += align((size_t)n * 64 * 4);

  dim3 blk(256);
  const int nbN = (n + 255) / 256;
  const int nbE2 = (int)((E / 2 + 255) / 256);  // 2 edges per thread
  const int nb  = (n + 1023) / 1024;            // scan chunks (<=64)
  const int nbW = (n + 3) / 4;                  // 4 waves/block kernels
  const int nbG = (n + 127) / 128;              // thread-per-node GEMMs

  k_detect<<<1, 256, 0, stream>>>((const unsigned long long*)EI, flag);
  k_zero<<<nbN, blk, 0, stream>>>(count, n);
  k_hist<<<nbE2, blk, 0, stream>>>(EI, flag, count, slot, E);

  // CSR build
  k_scansum<<<nb, blk, 0, stream>>>(count, bsum, n);
  k_scanoffsets<<<1, 64, 0, stream>>>(bsum, rowptr, nb, n);
  k_scanwrite<<<nb, blk, 0, stream>>>(count, bsum, rowptr, n);
  k_permute<<<nbE2, blk, 0, stream>>>(EI, flag, EW, rowptr, slot, edges, E);

  // degree + rsqrt from CSR rows
  k_deg_rsqrt<<<nbW, blk, 0, stream>>>(edges, rowptr, dis, n);

  // layer 1
  k_gemm1<<<nbG, dim3(128), 0, stream>>>(X, W1, A, n);
  k_gather<0><<<nbW, blk, 0, stream>>>(A, dis, edges, rowptr, b1, Wl, bl, B, n);

  // layer 2 (relu fused into gemm2 read; readout fused into gather epilogue)
  k_gemm2<<<nbG, dim3(128), 0, stream>>>(B, W2, A, n);
  k_gather<1><<<nbW, blk, 0, stream>>>(A, dis, edges, rowptr, b2, Wl, bl, out, n);
}

// Round 7
// 306.557 us; speedup vs baseline: 3.5363x; 1.0599x over previous
//
#include <hip/hip_runtime.h>

typedef _Float16 half8 __attribute__((ext_vector_type(8)));

#define HB 256      // histogram/permute blocks (edge chunks)
#define HT 512      // threads per histogram/permute block
#define KMAX 16     // max edges per thread in a chunk (supports E <= HB*HT*KMAX = 2.1M)
#define PASS 32768  // dsts covered per LDS pass (even); 2 passes cover n <= 65536

// ---------- helpers ----------
__device__ __forceinline__ long ld_idx(const void* idx, long pos, int is64) {
  return is64 ? (long)((const long long*)idx)[pos]
              : (long)((const int*)idx)[pos];
}

// Detect whether edge_index is int64 (flag=1) or int32 (flag=0).
__global__ void k_detect(const unsigned long long* __restrict__ p, int* __restrict__ flag) {
  if (threadIdx.x == 0) *flag = 1;
  __syncthreads();
  if (p[threadIdx.x] >= (1ULL << 32)) atomicExch(flag, 0);
}

// ---------- per-block LDS histogram: hist[b][d] (u16) + local slot per edge ----------
__global__ __launch_bounds__(HT) void k_hist(const void* __restrict__ idx,
                                             const int* __restrict__ flag,
                                             unsigned short* __restrict__ hist,
                                             unsigned short* __restrict__ slot,
                                             int n, long E, int chunk) {
  __shared__ unsigned int lds[PASS / 2];  // 64 KB, 2 packed u16 counters per word
  const int b = blockIdx.x, t = threadIdx.x;
  const long e0 = (long)b * chunk;
  long e1 = e0 + chunk; if (e1 > E) e1 = E;
  const int is64 = *flag;
  int dcache[KMAX];
  {
    int k = 0;
    for (long e = e0 + t; e < e1; e += HT, ++k) dcache[k] = (int)ld_idx(idx, E + e, is64);
  }
  const int npass = (n + PASS - 1) / PASS;
  for (int p = 0; p < npass; ++p) {
    const int d0 = p * PASS;
    for (int i = t; i < PASS / 2; i += HT) lds[i] = 0;
    __syncthreads();
    int k = 0;
    for (long e = e0 + t; e < e1; e += HT, ++k) {
      int d = dcache[k] - d0;
      if ((unsigned)d < (unsigned)PASS) {
        unsigned sh = (d & 1) * 16;
        unsigned old = atomicAdd(&lds[d >> 1], 1u << sh);
        slot[e] = (unsigned short)((old >> sh) & 0xffffu);
      }
    }
    __syncthreads();
    // flush slice [d0, d0+lim) of this block's row (n even -> u32-aligned, lim even)
    int lim = n - d0; if (lim > PASS) lim = PASS;
    unsigned int* hrow32 = (unsigned int*)(hist + (size_t)b * n + d0);
    for (int i = t; i < (lim + 1) / 2; i += HT) hrow32[i] = lds[i];
    __syncthreads();
  }
}

// ---------- column scan: per-(block,dst) exclusive base + per-dst totals ----------
__global__ __launch_bounds__(256) void k_colscan(const unsigned short* __restrict__ hist,
                                                 unsigned short* __restrict__ base,
                                                 int* __restrict__ total, int n) {
  int d = blockIdx.x * 256 + threadIdx.x;
  if (d >= n) return;
  unsigned acc = 0;
  for (int b = 0; b < HB; ++b) {
    size_t o = (size_t)b * n + d;
    unsigned c = hist[o];
    base[o] = (unsigned short)acc;
    acc += c;
  }
  total[d] = (int)acc;
}

// ---------- scan (exclusive prefix sum of total -> rowptr) ----------
__global__ __launch_bounds__(256) void k_scansum(const int* __restrict__ count, int* __restrict__ bsum, int n) {
  __shared__ int sh[256];
  int t = threadIdx.x;
  int base = blockIdx.x * 1024 + t * 4;
  int s = 0;
#pragma unroll
  for (int k = 0; k < 4; ++k) { int i = base + k; if (i < n) s += count[i]; }
  sh[t] = s; __syncthreads();
  for (int off = 128; off > 0; off >>= 1) {
    if (t < off) sh[t] += sh[t + off];
    __syncthreads();
  }
  if (t == 0) bsum[blockIdx.x] = sh[0];
}

__global__ void k_scanoffsets(int* __restrict__ bsum, int* __restrict__ rowptr, int nb, int n) {
  int t = threadIdx.x;  // 64 threads
  int v = (t < nb) ? bsum[t] : 0;
  int inc = v;
#pragma unroll
  for (int off = 1; off < 64; off <<= 1) {
    int u = __shfl_up(inc, off);
    if (t >= off) inc += u;
  }
  if (t < nb) bsum[t] = inc - v;      // exclusive
  if (t == nb - 1) rowptr[n] = inc;   // total = E
}

__global__ __launch_bounds__(256) void k_scanwrite(const int* __restrict__ count,
                                                   const int* __restrict__ bsum,
                                                   int* __restrict__ rowptr, int n) {
  __shared__ int sh[256];
  int t = threadIdx.x;
  int base = blockIdx.x * 1024 + t * 4;
  int c[4]; int s = 0;
#pragma unroll
  for (int k = 0; k < 4; ++k) { int i = base + k; c[k] = (i < n) ? count[i] : 0; s += c[k]; }
  sh[t] = s; __syncthreads();
  for (int off = 1; off < 256; off <<= 1) {
    int u = (t >= off) ? sh[t - off] : 0;
    __syncthreads();
    sh[t] += u;
    __syncthreads();
  }
  int excl = sh[t] - s + bsum[blockIdx.x];
#pragma unroll
  for (int k = 0; k < 4; ++k) {
    int i = base + k;
    if (i < n) rowptr[i] = excl;
    excl += c[k];
  }
}

// ---------- permute edges into CSR-by-dst (atomic-free), payload = (src, w) ----------
__global__ __launch_bounds__(HT) void k_permute(const void* __restrict__ idx,
                                                const int* __restrict__ flag,
                                                const float* __restrict__ w,
                                                const int* __restrict__ rowptr,
                                                const unsigned short* __restrict__ slot,
                                                const unsigned short* __restrict__ base,
                                                float2* __restrict__ edges,
                                                int n, long E, int chunk) {
  const int b = blockIdx.x, t = threadIdx.x;
  const long e0 = (long)b * chunk;
  long e1 = e0 + chunk; if (e1 > E) e1 = E;
  const int is64 = *flag;
  const unsigned short* brow = base + (size_t)b * n;  // this block's 100 KB base row
  for (long e = e0 + t; e < e1; e += HT) {
    long s = ld_idx(idx, e, is64);
    long d = ld_idx(idx, E + e, is64);
    int pos = rowptr[d] + (int)brow[d] + (int)slot[e];
    edges[pos] = make_float2(__int_as_float((int)s), w[e]);
  }
}

// ---------- weighted degree from CSR rows + fused rsqrt: dis[i] = rsqrt(1 + sum w) ----------
__global__ __launch_bounds__(256) void k_deg_rsqrt(const float2* __restrict__ edges,
                                                   const int* __restrict__ rowptr,
                                                   float* __restrict__ dis, int n) {
  int lane = threadIdx.x & 63;
  int node = blockIdx.x * 4 + (threadIdx.x >> 6);
  if (node >= n) return;
  int beg = rowptr[node], end = rowptr[node + 1];
  float s = 0.0f;
  for (int i = beg + lane; i < end; i += 64) s += edges[i].y;
#pragma unroll
  for (int off = 32; off > 0; off >>= 1) s += __shfl_down(s, off);
  if (lane == 0) dis[node] = rsqrtf(1.0f + s);   // deg >= 1 always (self-loop)
}

// ---------- dense layers: thread = node, 64 accumulators, W broadcast from LDS ----------
// h[n,64] = X[n,128] @ W[128,64], store fp16
__global__ __launch_bounds__(128) void k_gemm1(const float* __restrict__ X,
                                               const float* __restrict__ W,
                                               _Float16* __restrict__ h, int n) {
  __shared__ float Ws[128 * 64];
  for (int i = threadIdx.x; i < 2048; i += 128)
    ((float4*)Ws)[i] = ((const float4*)W)[i];
  __syncthreads();
  int node = blockIdx.x * 128 + threadIdx.x;
  if (node >= n) return;
  const float4* xr4 = (const float4*)(X + (size_t)node * 128);
  float acc[64];
#pragma unroll
  for (int f = 0; f < 64; ++f) acc[f] = 0.0f;
  for (int k4 = 0; k4 < 32; ++k4) {
    float4 x = xr4[k4];
#pragma unroll
    for (int kk = 0; kk < 4; ++kk) {
      float xv = (kk == 0) ? x.x : (kk == 1) ? x.y : (kk == 2) ? x.z : x.w;
      const float4* wrow = (const float4*)(Ws + (k4 * 4 + kk) * 64);
#pragma unroll
      for (int f4 = 0; f4 < 16; ++f4) {
        float4 w = wrow[f4];
        acc[f4 * 4 + 0] = fmaf(xv, w.x, acc[f4 * 4 + 0]);
        acc[f4 * 4 + 1] = fmaf(xv, w.y, acc[f4 * 4 + 1]);
        acc[f4 * 4 + 2] = fmaf(xv, w.z, acc[f4 * 4 + 2]);
        acc[f4 * 4 + 3] = fmaf(xv, w.w, acc[f4 * 4 + 3]);
      }
    }
  }
  _Float16* hp = h + (size_t)node * 64;
#pragma unroll
  for (int g = 0; g < 8; ++g) {
    half8 o;
#pragma unroll
    for (int i = 0; i < 8; ++i) o[i] = (_Float16)acc[g * 8 + i];
    *(half8*)(hp + g * 8) = o;
  }
}

// h[n,64] = relu(in[n,64]) @ W[64,64], store fp16
__global__ __launch_bounds__(128) void k_gemm2(const float* __restrict__ in,
                                               const float* __restrict__ W,
                                               _Float16* __restrict__ h, int n) {
  __shared__ float Ws[64 * 64];
  for (int i = threadIdx.x; i < 1024; i += 128)
    ((float4*)Ws)[i] = ((const float4*)W)[i];
  __syncthreads();
  int node = blockIdx.x * 128 + threadIdx.x;
  if (node >= n) return;
  const float4* xr4 = (const float4*)(in + (size_t)node * 64);
  float acc[64];
#pragma unroll
  for (int f = 0; f < 64; ++f) acc[f] = 0.0f;
  for (int k4 = 0; k4 < 16; ++k4) {
    float4 x = xr4[k4];
#pragma unroll
    for (int kk = 0; kk < 4; ++kk) {
      float xv = (kk == 0) ? x.x : (kk == 1) ? x.y : (kk == 2) ? x.z : x.w;
      xv = fmaxf(xv, 0.0f);  // relu fused
      const float4* wrow = (const float4*)(Ws + (k4 * 4 + kk) * 64);
#pragma unroll
      for (int f4 = 0; f4 < 16; ++f4) {
        float4 w = wrow[f4];
        acc[f4 * 4 + 0] = fmaf(xv, w.x, acc[f4 * 4 + 0]);
        acc[f4 * 4 + 1] = fmaf(xv, w.y, acc[f4 * 4 + 1]);
        acc[f4 * 4 + 2] = fmaf(xv, w.z, acc[f4 * 4 + 2]);
        acc[f4 * 4 + 3] = fmaf(xv, w.w, acc[f4 * 4 + 3]);
      }
    }
  }
  _Float16* hp = h + (size_t)node * 64;
#pragma unroll
  for (int g = 0; g < 8; ++g) {
    half8 o;
#pragma unroll
    for (int i = 0; i < 8; ++i) o[i] = (_Float16)acc[g * 8 + i];
    *(half8*)(hp + g * 8) = o;
  }
}

// ---------- pull-gather: one wave per dst node ----------
// lane = eg*8 + fl: 8 lanes cover 64 features (half8 = 16B each), 8 edge-groups in flight.
// MODE 0: out[node*64 + f] = b[f] + aggregate (fp32 row)
// MODE 1: out[node] = sigmoid( relu(b + aggregate) . Wl + bl )
template <int MODE>
__global__ __launch_bounds__(256) void k_gather(const _Float16* __restrict__ h,
                                                const float* __restrict__ dis,
                                                const float2* __restrict__ edges,
                                                const int* __restrict__ rowptr,
                                                const float* __restrict__ b,
                                                const float* __restrict__ Wl,
                                                const float* __restrict__ bl,
                                                float* __restrict__ out, int n) {
  int lane = threadIdx.x & 63;
  int fl = lane & 7;    // feature group (features fl*8 .. fl*8+7)
  int eg = lane >> 3;   // edge group 0..7
  int node = blockIdx.x * 4 + (threadIdx.x >> 6);
  if (node >= n) return;
  int beg = rowptr[node], end = rowptr[node + 1];
  float s0 = dis[node];
  float acc[8];
#pragma unroll
  for (int i = 0; i < 8; ++i) acc[i] = 0.0f;

  for (int base = beg; base < end; base += 64) {
    int m = end - base; if (m > 64) m = 64;
    float2 pk = (lane < m) ? edges[base + lane] : make_float2(__int_as_float(0), 0.0f);
    float nrm = dis[__float_as_int(pk.x)] * pk.y * s0;
    int steps = (m + 7) >> 3;
    for (int s = 0; s < steps; ++s) {
      int j = s * 8 + eg;
      int   sj = __float_as_int(__shfl(pk.x, j));
      float nj = __shfl(nrm, j);
      half8 hv = *(const half8*)(h + (size_t)sj * 64 + fl * 8);
#pragma unroll
      for (int i = 0; i < 8; ++i) acc[i] = fmaf((float)hv[i], nj, acc[i]);
    }
  }
#pragma unroll
  for (int off = 8; off < 64; off <<= 1)
#pragma unroll
    for (int i = 0; i < 8; ++i) acc[i] += __shfl_xor(acc[i], off);

  // bias + self-loop message
  half8 hs = *(const half8*)(h + (size_t)node * 64 + fl * 8);
  float4 bv0 = *(const float4*)(b + fl * 8);
  float4 bv1 = *(const float4*)(b + fl * 8 + 4);
  float bb[8] = {bv0.x, bv0.y, bv0.z, bv0.w, bv1.x, bv1.y, bv1.z, bv1.w};
  float s2 = s0 * s0;
#pragma unroll
  for (int i = 0; i < 8; ++i) acc[i] += bb[i] + (float)hs[i] * s2;

  if (MODE == 0) {
    if (eg == 0) {
      float4 o0 = make_float4(acc[0], acc[1], acc[2], acc[3]);
      float4 o1 = make_float4(acc[4], acc[5], acc[6], acc[7]);
      *(float4*)(out + (size_t)node * 64 + fl * 8) = o0;
      *(float4*)(out + (size_t)node * 64 + fl * 8 + 4) = o1;
    }
  } else {
    float4 wl0 = *(const float4*)(Wl + fl * 8);
    float4 wl1 = *(const float4*)(Wl + fl * 8 + 4);
    float wl[8] = {wl0.x, wl0.y, wl0.z, wl0.w, wl1.x, wl1.y, wl1.z, wl1.w};
    float v = 0.0f;
#pragma unroll
    for (int i = 0; i < 8; ++i) v += fmaxf(acc[i], 0.0f) * wl[i];
#pragma unroll
    for (int off = 1; off < 8; off <<= 1) v += __shfl_xor(v, off);
    if (lane == 0) out[node] = 1.0f / (1.0f + expf(-(v + bl[0])));
  }
}

extern "C" void kernel_launch(void* const* d_in, const int* in_sizes, int n_in,
                              void* d_out, int out_size, void* d_ws, size_t ws_size,
                              hipStream_t stream) {
  const float* X  = (const float*)d_in[0];
  const void*  EI = d_in[1];
  const float* EW = (const float*)d_in[2];
  const float* W1 = (const float*)d_in[3];
  const float* b1 = (const float*)d_in[4];
  const float* W2 = (const float*)d_in[5];
  const float* b2 = (const float*)d_in[6];
  const float* Wl = (const float*)d_in[7];
  const float* bl = (const float*)d_in[8];
  float* out = (float*)d_out;

  const int  n = in_sizes[0] / 128;      // 50000 (even)
  const long E = (long)in_sizes[1] / 2;  // 1,600,000

  auto align = [](size_t x) { return (x + 255) & ~(size_t)255; };
  char* ws = (char*)d_ws;
  size_t off = 0;
  int*            flag   = (int*)(ws + off);            off += 256;
  float*          dis    = (float*)(ws + off);          off += align((size_t)n * 4);
  int*            total  = (int*)(ws + off);            off += align((size_t)n * 4);
  int*            rowptr = (int*)(ws + off);            off += align((size_t)(n + 1) * 4);
  int*            bsum   = (int*)(ws + off);            off += 256;
  unsigned short* slot   = (unsigned short*)(ws + off); off += align((size_t)E * 2);
  unsigned short* hist   = (unsigned short*)(ws + off); off += align((size_t)HB * n * 2);
  unsigned short* basep  = (unsigned short*)(ws + off); off += align((size_t)HB * n * 2);
  float2*         edges  = (float2*)(ws + off);         off += align((size_t)E * 8);
  _Float16*       A      = (_Float16*)(ws + off);       off += align((size_t)n * 64 * 2);
  float*          B      = (float*)(ws + off);          off += align((size_t)n * 64 * 4);

  dim3 blk(256);
  const int chunk = (int)((E + HB - 1) / HB);   // 6250
  const int nb  = (n + 1023) / 1024;            // scan chunks (<=64)
  const int nbW = (n + 3) / 4;                  // 4 waves/block kernels
  const int nbG = (n + 127) / 128;              // thread-per-node GEMMs

  k_detect<<<1, 256, 0, stream>>>((const unsigned long long*)EI, flag);
  k_hist<<<HB, dim3(HT), 0, stream>>>(EI, flag, hist, slot, n, E, chunk);
  k_colscan<<<(n + 255) / 256, blk, 0, stream>>>(hist, basep, total, n);

  // CSR rowptr from totals
  k_scansum<<<nb, blk, 0, stream>>>(total, bsum, n);
  k_scanoffsets<<<1, 64, 0, stream>>>(bsum, rowptr, nb, n);
  k_scanwrite<<<nb, blk, 0, stream>>>(total, bsum, rowptr, n);
  k_permute<<<HB, dim3(HT), 0, stream>>>(EI, flag, EW, rowptr, slot, basep, edges, n, E, chunk);

  // degree + rsqrt from CSR rows
  k_deg_rsqrt<<<nbW, blk, 0, stream>>>(edges, rowptr, dis, n);

  // layer 1
  k_gemm1<<<nbG, dim3(128), 0, stream>>>(X, W1, A, n);
  k_gather<0><<<nbW, blk, 0, stream>>>(A, dis, edges, rowptr, b1, Wl, bl, B, n);

  // layer 2 (relu fused into gemm2 read; readout fused into gather epilogue)
  k_gemm2<<<nbG, dim3(128), 0, stream>>>(B, W2, A, n);
  k_gather<1><<<nbW, blk, 0, stream>>>(A, dis, edges, rowptr, b2, Wl, bl, out, n);
}

// Round 8
// 281.200 us; speedup vs baseline: 3.8551x; 1.0902x over previous
//
#include <hip/hip_runtime.h>

typedef _Float16 half8 __attribute__((ext_vector_type(8)));

#define A2B 512   // edge chunks (A1/A2 blocks)
#define A2T 512   // threads in A2
#define STG 3200  // staged records per chunk (>= ceil(E/A2B))

// ---------- helpers ----------
__device__ __forceinline__ long ld_idx(const void* idx, long pos, int is64) {
  return is64 ? (long)((const long long*)idx)[pos]
              : (long)((const int*)idx)[pos];
}

// Detect whether edge_index is int64 (flag=1) or int32 (flag=0).
__global__ void k_detect(const unsigned long long* __restrict__ p, int* __restrict__ flag) {
  if (threadIdx.x == 0) *flag = 1;
  __syncthreads();
  if (p[threadIdx.x] >= (1ULL << 32)) atomicExch(flag, 0);
}

// ---------- A1: coarse 256-bucket histogram per edge chunk ----------
__global__ __launch_bounds__(256) void k_hist256(const void* __restrict__ idx,
                                                 const int* __restrict__ flag,
                                                 unsigned* __restrict__ hist256,
                                                 long E, int chunk, unsigned M) {
  __shared__ unsigned cnt[256];
  const int b = blockIdx.x, t = threadIdx.x;
  cnt[t] = 0;
  __syncthreads();
  const long e0 = (long)b * chunk;
  long e1 = e0 + chunk; if (e1 > E) e1 = E;
  const int is64 = *flag;
  for (long e = e0 + t; e < e1; e += 256) {
    unsigned d = (unsigned)ld_idx(idx, E + e, is64);
    atomicAdd(&cnt[__umulhi(d, M)], 1u);
  }
  __syncthreads();
  hist256[b * 256 + t] = cnt[t];   // b-major: coalesced here and in C1/A2
}

// ---------- C1: bases for (chunk,bucket) + bucket starts (single block) ----------
__global__ __launch_bounds__(256) void k_scan256(const unsigned* __restrict__ hist256,
                                                 unsigned* __restrict__ base256,
                                                 int* __restrict__ bstart, long E) {
  __shared__ unsigned colsum[256], scanb[256];
  const int kk = threadIdx.x;
  unsigned run = 0;
  for (int b = 0; b < A2B; ++b) run += hist256[b * 256 + kk];
  colsum[kk] = run; scanb[kk] = run;
  __syncthreads();
  for (int off = 1; off < 256; off <<= 1) {
    unsigned u = (kk >= off) ? scanb[kk - off] : 0;
    __syncthreads();
    scanb[kk] += u;
    __syncthreads();
  }
  unsigned excl = scanb[kk] - colsum[kk];
  run = excl;
  for (int b = 0; b < A2B; ++b) {
    base256[b * 256 + kk] = run;
    run += hist256[b * 256 + kk];
  }
  bstart[kk] = (int)excl;
  if (kk == 255) bstart[256] = (int)E;
}

// ---------- A2: LDS counting-sort each chunk by bucket, write bucket-major recs ----------
__global__ __launch_bounds__(A2T) void k_bucket(const void* __restrict__ idx,
                                                const int* __restrict__ flag,
                                                const float* __restrict__ w,
                                                const unsigned* __restrict__ base256,
                                                int4* __restrict__ recs,
                                                long E, int chunk, unsigned M) {
  __shared__ int4 stage[STG];                       // 51.2 KB
  __shared__ unsigned cnt[256], lofs[256], lbase[256], bcol[256], scanb[256];
  const int b = blockIdx.x, t = threadIdx.x;
  const long e0 = (long)b * chunk;
  long e1 = e0 + chunk; if (e1 > E) e1 = E;
  const int m = (int)(e1 - e0);
  const int is64 = *flag;
  for (int i = t; i < 256; i += A2T) cnt[i] = 0;
  __syncthreads();
  int dc[8]; unsigned char kc[8];
  int nk = 0;
  for (long e = e0 + t; e < e1; e += A2T, ++nk) {
    int d = (int)ld_idx(idx, E + e, is64);
    unsigned kb = __umulhi((unsigned)d, M);
    dc[nk] = d; kc[nk] = (unsigned char)kb;
    atomicAdd(&cnt[kb], 1u);
  }
  __syncthreads();
  if (t < 256) { scanb[t] = cnt[t]; bcol[t] = base256[b * 256 + t]; }
  __syncthreads();
  for (int off = 1; off < 256; off <<= 1) {
    unsigned u = 0;
    if (t < 256 && t >= off) u = scanb[t - off];
    __syncthreads();
    if (t < 256) scanb[t] += u;
    __syncthreads();
  }
  if (t < 256) { unsigned ex = scanb[t] - cnt[t]; lbase[t] = ex; lofs[t] = ex; }
  __syncthreads();
  nk = 0;
  for (long e = e0 + t; e < e1; e += A2T, ++nk) {
    int s = (int)ld_idx(idx, e, is64);
    float wv = w[e];
    unsigned kb = kc[nk];
    unsigned pos = atomicAdd(&lofs[kb], 1u);
    stage[pos] = make_int4(s, __float_as_int(wv), dc[nk], 0);
  }
  __syncthreads();
  for (int i = t; i < m; i += A2T) {
    int4 r = stage[i];
    unsigned kb = __umulhi((unsigned)r.z, M);
    recs[bcol[kb] + (unsigned)i - lbase[kb]] = r;   // runs of consecutive addresses
  }
}

// ---------- B: one block per bucket; rowptr + dis + final CSR placement ----------
__global__ __launch_bounds__(1024) void k_build(const int4* __restrict__ recs,
                                                const int* __restrict__ bstart,
                                                int* __restrict__ rowptr,
                                                float* __restrict__ dis,
                                                float2* __restrict__ edges,
                                                int n, int dwidth, long E) {
  __shared__ float wsum[256];
  __shared__ unsigned cnt[256], lofs[256], scanb[256];
  const int k = blockIdx.x, t = threadIdx.x;
  const int d0 = k * dwidth;
  const int r0 = bstart[k], r1 = bstart[k + 1];
  const int m = r1 - r0;
  if (t < 256) { wsum[t] = 0.0f; cnt[t] = 0; }
  __syncthreads();
  for (int i = t; i < m; i += 1024) {
    int4 r = recs[r0 + i];
    int dl = r.z - d0;
    atomicAdd(&cnt[dl], 1u);
    atomicAdd(&wsum[dl], __int_as_float(r.y));
  }
  __syncthreads();
  if (t < 256) scanb[t] = cnt[t];
  __syncthreads();
  for (int off = 1; off < 256; off <<= 1) {
    unsigned u = 0;
    if (t < 256 && t >= off) u = scanb[t - off];
    __syncthreads();
    if (t < 256) scanb[t] += u;
    __syncthreads();
  }
  if (t < 256) {
    unsigned ex = scanb[t] - cnt[t];
    lofs[t] = (unsigned)r0 + ex;
    int d = d0 + t;
    if (t < dwidth && d < n) {
      rowptr[d] = r0 + (int)ex;
      dis[d] = rsqrtf(1.0f + wsum[t]);   // deg >= 1 (self-loop weight 1)
    }
  }
  if (k == gridDim.x - 1 && t == 0) rowptr[n] = (int)E;
  __syncthreads();
  for (int i = t; i < m; i += 1024) {
    int4 r = recs[r0 + i];
    unsigned pos = atomicAdd(&lofs[r.z - d0], 1u);
    edges[pos] = make_float2(__int_as_float(r.x), __int_as_float(r.y));  // L2-resident region
  }
}

// ---------- dense layers: thread = node, 64 accumulators, W broadcast from LDS ----------
__global__ __launch_bounds__(128) void k_gemm1(const float* __restrict__ X,
                                               const float* __restrict__ W,
                                               _Float16* __restrict__ h, int n) {
  __shared__ float Ws[128 * 64];
  for (int i = threadIdx.x; i < 2048; i += 128)
    ((float4*)Ws)[i] = ((const float4*)W)[i];
  __syncthreads();
  int node = blockIdx.x * 128 + threadIdx.x;
  if (node >= n) return;
  const float4* xr4 = (const float4*)(X + (size_t)node * 128);
  float acc[64];
#pragma unroll
  for (int f = 0; f < 64; ++f) acc[f] = 0.0f;
  for (int k4 = 0; k4 < 32; ++k4) {
    float4 x = xr4[k4];
#pragma unroll
    for (int kk = 0; kk < 4; ++kk) {
      float xv = (kk == 0) ? x.x : (kk == 1) ? x.y : (kk == 2) ? x.z : x.w;
      const float4* wrow = (const float4*)(Ws + (k4 * 4 + kk) * 64);
#pragma unroll
      for (int f4 = 0; f4 < 16; ++f4) {
        float4 w = wrow[f4];
        acc[f4 * 4 + 0] = fmaf(xv, w.x, acc[f4 * 4 + 0]);
        acc[f4 * 4 + 1] = fmaf(xv, w.y, acc[f4 * 4 + 1]);
        acc[f4 * 4 + 2] = fmaf(xv, w.z, acc[f4 * 4 + 2]);
        acc[f4 * 4 + 3] = fmaf(xv, w.w, acc[f4 * 4 + 3]);
      }
    }
  }
  _Float16* hp = h + (size_t)node * 64;
#pragma unroll
  for (int g = 0; g < 8; ++g) {
    half8 o;
#pragma unroll
    for (int i = 0; i < 8; ++i) o[i] = (_Float16)acc[g * 8 + i];
    *(half8*)(hp + g * 8) = o;
  }
}

__global__ __launch_bounds__(128) void k_gemm2(const float* __restrict__ in,
                                               const float* __restrict__ W,
                                               _Float16* __restrict__ h, int n) {
  __shared__ float Ws[64 * 64];
  for (int i = threadIdx.x; i < 1024; i += 128)
    ((float4*)Ws)[i] = ((const float4*)W)[i];
  __syncthreads();
  int node = blockIdx.x * 128 + threadIdx.x;
  if (node >= n) return;
  const float4* xr4 = (const float4*)(in + (size_t)node * 64);
  float acc[64];
#pragma unroll
  for (int f = 0; f < 64; ++f) acc[f] = 0.0f;
  for (int k4 = 0; k4 < 16; ++k4) {
    float4 x = xr4[k4];
#pragma unroll
    for (int kk = 0; kk < 4; ++kk) {
      float xv = (kk == 0) ? x.x : (kk == 1) ? x.y : (kk == 2) ? x.z : x.w;
      xv = fmaxf(xv, 0.0f);  // relu fused
      const float4* wrow = (const float4*)(Ws + (k4 * 4 + kk) * 64);
#pragma unroll
      for (int f4 = 0; f4 < 16; ++f4) {
        float4 w = wrow[f4];
        acc[f4 * 4 + 0] = fmaf(xv, w.x, acc[f4 * 4 + 0]);
        acc[f4 * 4 + 1] = fmaf(xv, w.y, acc[f4 * 4 + 1]);
        acc[f4 * 4 + 2] = fmaf(xv, w.z, acc[f4 * 4 + 2]);
        acc[f4 * 4 + 3] = fmaf(xv, w.w, acc[f4 * 4 + 3]);
      }
    }
  }
  _Float16* hp = h + (size_t)node * 64;
#pragma unroll
  for (int g = 0; g < 8; ++g) {
    half8 o;
#pragma unroll
    for (int i = 0; i < 8; ++i) o[i] = (_Float16)acc[g * 8 + i];
    *(half8*)(hp + g * 8) = o;
  }
}

// ---------- pull-gather: one wave per dst node ----------
template <int MODE>
__global__ __launch_bounds__(256) void k_gather(const _Float16* __restrict__ h,
                                                const float* __restrict__ dis,
                                                const float2* __restrict__ edges,
                                                const int* __restrict__ rowptr,
                                                const float* __restrict__ b,
                                                const float* __restrict__ Wl,
                                                const float* __restrict__ bl,
                                                float* __restrict__ out, int n) {
  int lane = threadIdx.x & 63;
  int fl = lane & 7;    // feature group (features fl*8 .. fl*8+7)
  int eg = lane >> 3;   // edge group 0..7
  int node = blockIdx.x * 4 + (threadIdx.x >> 6);
  if (node >= n) return;
  int beg = rowptr[node], end = rowptr[node + 1];
  float s0 = dis[node];
  float acc[8];
#pragma unroll
  for (int i = 0; i < 8; ++i) acc[i] = 0.0f;

  for (int base = beg; base < end; base += 64) {
    int m = end - base; if (m > 64) m = 64;
    float2 pk = (lane < m) ? edges[base + lane] : make_float2(__int_as_float(0), 0.0f);
    float nrm = dis[__float_as_int(pk.x)] * pk.y * s0;
    int steps = (m + 7) >> 3;
    for (int s = 0; s < steps; ++s) {
      int j = s * 8 + eg;
      int   sj = __float_as_int(__shfl(pk.x, j));
      float nj = __shfl(nrm, j);
      half8 hv = *(const half8*)(h + (size_t)sj * 64 + fl * 8);
#pragma unroll
      for (int i = 0; i < 8; ++i) acc[i] = fmaf((float)hv[i], nj, acc[i]);
    }
  }
#pragma unroll
  for (int off = 8; off < 64; off <<= 1)
#pragma unroll
    for (int i = 0; i < 8; ++i) acc[i] += __shfl_xor(acc[i], off);

  half8 hs = *(const half8*)(h + (size_t)node * 64 + fl * 8);
  float4 bv0 = *(const float4*)(b + fl * 8);
  float4 bv1 = *(const float4*)(b + fl * 8 + 4);
  float bb[8] = {bv0.x, bv0.y, bv0.z, bv0.w, bv1.x, bv1.y, bv1.z, bv1.w};
  float s2 = s0 * s0;
#pragma unroll
  for (int i = 0; i < 8; ++i) acc[i] += bb[i] + (float)hs[i] * s2;

  if (MODE == 0) {
    if (eg == 0) {
      float4 o0 = make_float4(acc[0], acc[1], acc[2], acc[3]);
      float4 o1 = make_float4(acc[4], acc[5], acc[6], acc[7]);
      *(float4*)(out + (size_t)node * 64 + fl * 8) = o0;
      *(float4*)(out + (size_t)node * 64 + fl * 8 + 4) = o1;
    }
  } else {
    float4 wl0 = *(const float4*)(Wl + fl * 8);
    float4 wl1 = *(const float4*)(Wl + fl * 8 + 4);
    float wl[8] = {wl0.x, wl0.y, wl0.z, wl0.w, wl1.x, wl1.y, wl1.z, wl1.w};
    float v = 0.0f;
#pragma unroll
    for (int i = 0; i < 8; ++i) v += fmaxf(acc[i], 0.0f) * wl[i];
#pragma unroll
    for (int off = 1; off < 8; off <<= 1) v += __shfl_xor(v, off);
    if (lane == 0) out[node] = 1.0f / (1.0f + expf(-(v + bl[0])));
  }
}

extern "C" void kernel_launch(void* const* d_in, const int* in_sizes, int n_in,
                              void* d_out, int out_size, void* d_ws, size_t ws_size,
                              hipStream_t stream) {
  const float* X  = (const float*)d_in[0];
  const void*  EI = d_in[1];
  const float* EW = (const float*)d_in[2];
  const float* W1 = (const float*)d_in[3];
  const float* b1 = (const float*)d_in[4];
  const float* W2 = (const float*)d_in[5];
  const float* b2 = (const float*)d_in[6];
  const float* Wl = (const float*)d_in[7];
  const float* bl = (const float*)d_in[8];
  float* out = (float*)d_out;

  const int  n = in_sizes[0] / 128;      // 50000
  const long E = (long)in_sizes[1] / 2;  // 1,600,000

  const int chunk  = (int)((E + A2B - 1) / A2B);       // 3125 (<= STG)
  const int dwidth = (n + 255) / 256;                  // 196  (<= 256 for n <= 65536)
  const unsigned M = (unsigned)((0x100000000ULL + (unsigned)dwidth - 1) / (unsigned)dwidth);

  auto align = [](size_t x) { return (x + 255) & ~(size_t)255; };
  char* ws = (char*)d_ws;
  size_t off = 0;
  int*      flag    = (int*)(ws + off);      off += 256;
  float*    dis     = (float*)(ws + off);    off += align((size_t)n * 4);
  int*      rowptr  = (int*)(ws + off);      off += align((size_t)(n + 1) * 4);
  int*      bstart  = (int*)(ws + off);      off += align(257 * 4);
  unsigned* hist256 = (unsigned*)(ws + off); off += align((size_t)A2B * 256 * 4);
  unsigned* base256 = (unsigned*)(ws + off); off += align((size_t)A2B * 256 * 4);
  int4*     recs    = (int4*)(ws + off);     off += align((size_t)E * 16);
  float2*   edges   = (float2*)(ws + off);   off += align((size_t)E * 8);
  _Float16* A       = (_Float16*)(ws + off); off += align((size_t)n * 64 * 2);
  float*    B       = (float*)(ws + off);    off += align((size_t)n * 64 * 4);

  const int nbW = (n + 3) / 4;     // 4 waves/block gathers
  const int nbG = (n + 127) / 128; // thread-per-node GEMMs

  k_detect<<<1, 256, 0, stream>>>((const unsigned long long*)EI, flag);
  k_hist256<<<A2B, 256, 0, stream>>>(EI, flag, hist256, E, chunk, M);
  k_scan256<<<1, 256, 0, stream>>>(hist256, base256, bstart, E);
  k_bucket<<<A2B, A2T, 0, stream>>>(EI, flag, EW, base256, recs, E, chunk, M);
  k_build<<<256, 1024, 0, stream>>>(recs, bstart, rowptr, dis, edges, n, dwidth, E);

  // layer 1
  k_gemm1<<<nbG, dim3(128), 0, stream>>>(X, W1, A, n);
  k_gather<0><<<nbW, dim3(256), 0, stream>>>(A, dis, edges, rowptr, b1, Wl, bl, B, n);

  // layer 2 (relu fused into gemm2 read; readout fused into gather epilogue)
  k_gemm2<<<nbG, dim3(128), 0, stream>>>(B, W2, A, n);
  k_gather<1><<<nbW, dim3(256), 0, stream>>>(A, dis, edges, rowptr, b2, Wl, bl, out, n);
}

// Round 9
// 260.928 us; speedup vs baseline: 4.1547x; 1.0777x over previous
//
#include <hip/hip_runtime.h>

typedef _Float16 half8 __attribute__((ext_vector_type(8)));

#define A2B 512   // edge chunks (A1/A2 blocks)
#define A2T 512   // threads in A2
#define STG 3200  // staged records per chunk (>= ceil(E/A2B))

// ---------- helpers ----------
__device__ __forceinline__ long ld_idx(const void* idx, long pos, int is64) {
  return is64 ? (long)((const long long*)idx)[pos]
              : (long)((const int*)idx)[pos];
}

// Detect whether edge_index is int64 (flag=1) or int32 (flag=0).
__global__ void k_detect(const unsigned long long* __restrict__ p, int* __restrict__ flag) {
  if (threadIdx.x == 0) *flag = 1;
  __syncthreads();
  if (p[threadIdx.x] >= (1ULL << 32)) atomicExch(flag, 0);
}

// ---------- A1: coarse 256-bucket histogram per edge chunk ----------
__global__ __launch_bounds__(256) void k_hist256(const void* __restrict__ idx,
                                                 const int* __restrict__ flag,
                                                 unsigned* __restrict__ hist256,
                                                 long E, int chunk, unsigned M) {
  __shared__ unsigned cnt[256];
  const int b = blockIdx.x, t = threadIdx.x;
  cnt[t] = 0;
  __syncthreads();
  const long e0 = (long)b * chunk;
  long e1 = e0 + chunk; if (e1 > E) e1 = E;
  const int is64 = *flag;
  for (long e = e0 + t; e < e1; e += 256) {
    unsigned d = (unsigned)ld_idx(idx, E + e, is64);
    atomicAdd(&cnt[__umulhi(d, M)], 1u);
  }
  __syncthreads();
  hist256[b * 256 + t] = cnt[t];   // b-major: coalesced here and in C1/A2
}

// ---------- C1: bases for (chunk,bucket) + bucket starts (single block) ----------
__global__ __launch_bounds__(256) void k_scan256(const unsigned* __restrict__ hist256,
                                                 unsigned* __restrict__ base256,
                                                 int* __restrict__ bstart, long E) {
  __shared__ unsigned colsum[256], scanb[256];
  const int kk = threadIdx.x;
  unsigned run = 0;
  for (int b = 0; b < A2B; ++b) run += hist256[b * 256 + kk];
  colsum[kk] = run; scanb[kk] = run;
  __syncthreads();
  for (int off = 1; off < 256; off <<= 1) {
    unsigned u = (kk >= off) ? scanb[kk - off] : 0;
    __syncthreads();
    scanb[kk] += u;
    __syncthreads();
  }
  unsigned excl = scanb[kk] - colsum[kk];
  run = excl;
  for (int b = 0; b < A2B; ++b) {
    base256[b * 256 + kk] = run;
    run += hist256[b * 256 + kk];
  }
  bstart[kk] = (int)excl;
  if (kk == 255) bstart[256] = (int)E;
}

// ---------- A2: LDS counting-sort each chunk by bucket, write bucket-major recs ----------
__global__ __launch_bounds__(A2T) void k_bucket(const void* __restrict__ idx,
                                                const int* __restrict__ flag,
                                                const float* __restrict__ w,
                                                const unsigned* __restrict__ base256,
                                                int4* __restrict__ recs,
                                                long E, int chunk, unsigned M) {
  __shared__ int4 stage[STG];                       // 51.2 KB
  __shared__ unsigned cnt[256], lofs[256], lbase[256], bcol[256], scanb[256];
  const int b = blockIdx.x, t = threadIdx.x;
  const long e0 = (long)b * chunk;
  long e1 = e0 + chunk; if (e1 > E) e1 = E;
  const int m = (int)(e1 - e0);
  const int is64 = *flag;
  for (int i = t; i < 256; i += A2T) cnt[i] = 0;
  __syncthreads();
  int dc[8]; unsigned char kc[8];
  int nk = 0;
  for (long e = e0 + t; e < e1; e += A2T, ++nk) {
    int d = (int)ld_idx(idx, E + e, is64);
    unsigned kb = __umulhi((unsigned)d, M);
    dc[nk] = d; kc[nk] = (unsigned char)kb;
    atomicAdd(&cnt[kb], 1u);
  }
  __syncthreads();
  if (t < 256) { scanb[t] = cnt[t]; bcol[t] = base256[b * 256 + t]; }
  __syncthreads();
  for (int off = 1; off < 256; off <<= 1) {
    unsigned u = 0;
    if (t < 256 && t >= off) u = scanb[t - off];
    __syncthreads();
    if (t < 256) scanb[t] += u;
    __syncthreads();
  }
  if (t < 256) { unsigned ex = scanb[t] - cnt[t]; lbase[t] = ex; lofs[t] = ex; }
  __syncthreads();
  nk = 0;
  for (long e = e0 + t; e < e1; e += A2T, ++nk) {
    int s = (int)ld_idx(idx, e, is64);
    float wv = w[e];
    unsigned kb = kc[nk];
    unsigned pos = atomicAdd(&lofs[kb], 1u);
    stage[pos] = make_int4(s, __float_as_int(wv), dc[nk], 0);
  }
  __syncthreads();
  for (int i = t; i < m; i += A2T) {
    int4 r = stage[i];
    unsigned kb = __umulhi((unsigned)r.z, M);
    recs[bcol[kb] + (unsigned)i - lbase[kb]] = r;   // runs of consecutive addresses
  }
}

// ---------- B: one block per bucket; rowptr + dis + final CSR placement ----------
__global__ __launch_bounds__(1024) void k_build(const int4* __restrict__ recs,
                                                const int* __restrict__ bstart,
                                                int* __restrict__ rowptr,
                                                float* __restrict__ dis,
                                                float2* __restrict__ edges,
                                                int n, int dwidth, long E) {
  __shared__ float wsum[256];
  __shared__ unsigned cnt[256], lofs[256], scanb[256];
  const int k = blockIdx.x, t = threadIdx.x;
  const int d0 = k * dwidth;
  const int r0 = bstart[k], r1 = bstart[k + 1];
  const int m = r1 - r0;
  if (t < 256) { wsum[t] = 0.0f; cnt[t] = 0; }
  __syncthreads();
  for (int i = t; i < m; i += 1024) {
    int4 r = recs[r0 + i];
    int dl = r.z - d0;
    atomicAdd(&cnt[dl], 1u);
    atomicAdd(&wsum[dl], __int_as_float(r.y));
  }
  __syncthreads();
  if (t < 256) scanb[t] = cnt[t];
  __syncthreads();
  for (int off = 1; off < 256; off <<= 1) {
    unsigned u = 0;
    if (t < 256 && t >= off) u = scanb[t - off];
    __syncthreads();
    if (t < 256) scanb[t] += u;
    __syncthreads();
  }
  if (t < 256) {
    unsigned ex = scanb[t] - cnt[t];
    lofs[t] = (unsigned)r0 + ex;
    int d = d0 + t;
    if (t < dwidth && d < n) {
      rowptr[d] = r0 + (int)ex;
      dis[d] = rsqrtf(1.0f + wsum[t]);   // deg >= 1 (self-loop weight 1)
    }
  }
  if (k == gridDim.x - 1 && t == 0) rowptr[n] = (int)E;
  __syncthreads();
  for (int i = t; i < m; i += 1024) {
    int4 r = recs[r0 + i];
    unsigned pos = atomicAdd(&lofs[r.z - d0], 1u);
    edges[pos] = make_float2(__int_as_float(r.x), __int_as_float(r.y));  // L2-resident region
  }
}

// ---------- dense layers: 4 threads per node (16 outputs each), W broadcast from LDS ----------
// h[n,64] = X[n,128] @ W[128,64], store fp16
__global__ __launch_bounds__(256) void k_gemm1(const float* __restrict__ X,
                                               const float* __restrict__ W,
                                               _Float16* __restrict__ h, int n) {
  __shared__ float Ws[128 * 64];
  for (int i = threadIdx.x; i < 2048; i += 256)
    ((float4*)Ws)[i] = ((const float4*)W)[i];
  __syncthreads();
  int gid = blockIdx.x * 256 + threadIdx.x;
  int node = gid >> 2;
  int fg = (gid & 3) * 16;   // this thread's 16-feature slice
  if (node >= n) return;
  const float4* xr4 = (const float4*)(X + (size_t)node * 128);
  float acc[16];
#pragma unroll
  for (int f = 0; f < 16; ++f) acc[f] = 0.0f;
  for (int k4 = 0; k4 < 32; ++k4) {
    float4 x = xr4[k4];
#pragma unroll
    for (int kk = 0; kk < 4; ++kk) {
      float xv = (kk == 0) ? x.x : (kk == 1) ? x.y : (kk == 2) ? x.z : x.w;
      const float4* wrow = (const float4*)(Ws + (k4 * 4 + kk) * 64 + fg);
#pragma unroll
      for (int f4 = 0; f4 < 4; ++f4) {
        float4 w = wrow[f4];
        acc[f4 * 4 + 0] = fmaf(xv, w.x, acc[f4 * 4 + 0]);
        acc[f4 * 4 + 1] = fmaf(xv, w.y, acc[f4 * 4 + 1]);
        acc[f4 * 4 + 2] = fmaf(xv, w.z, acc[f4 * 4 + 2]);
        acc[f4 * 4 + 3] = fmaf(xv, w.w, acc[f4 * 4 + 3]);
      }
    }
  }
  _Float16* hp = h + (size_t)node * 64 + fg;
#pragma unroll
  for (int g = 0; g < 2; ++g) {
    half8 o;
#pragma unroll
    for (int i = 0; i < 8; ++i) o[i] = (_Float16)acc[g * 8 + i];
    *(half8*)(hp + g * 8) = o;
  }
}

// h[n,64] = relu(in[n,64]) @ W[64,64], store fp16
__global__ __launch_bounds__(256) void k_gemm2(const float* __restrict__ in,
                                               const float* __restrict__ W,
                                               _Float16* __restrict__ h, int n) {
  __shared__ float Ws[64 * 64];
  for (int i = threadIdx.x; i < 1024; i += 256)
    ((float4*)Ws)[i] = ((const float4*)W)[i];
  __syncthreads();
  int gid = blockIdx.x * 256 + threadIdx.x;
  int node = gid >> 2;
  int fg = (gid & 3) * 16;
  if (node >= n) return;
  const float4* xr4 = (const float4*)(in + (size_t)node * 64);
  float acc[16];
#pragma unroll
  for (int f = 0; f < 16; ++f) acc[f] = 0.0f;
  for (int k4 = 0; k4 < 16; ++k4) {
    float4 x = xr4[k4];
#pragma unroll
    for (int kk = 0; kk < 4; ++kk) {
      float xv = (kk == 0) ? x.x : (kk == 1) ? x.y : (kk == 2) ? x.z : x.w;
      xv = fmaxf(xv, 0.0f);  // relu fused
      const float4* wrow = (const float4*)(Ws + (k4 * 4 + kk) * 64 + fg);
#pragma unroll
      for (int f4 = 0; f4 < 4; ++f4) {
        float4 w = wrow[f4];
        acc[f4 * 4 + 0] = fmaf(xv, w.x, acc[f4 * 4 + 0]);
        acc[f4 * 4 + 1] = fmaf(xv, w.y, acc[f4 * 4 + 1]);
        acc[f4 * 4 + 2] = fmaf(xv, w.z, acc[f4 * 4 + 2]);
        acc[f4 * 4 + 3] = fmaf(xv, w.w, acc[f4 * 4 + 3]);
      }
    }
  }
  _Float16* hp = h + (size_t)node * 64 + fg;
#pragma unroll
  for (int g = 0; g < 2; ++g) {
    half8 o;
#pragma unroll
    for (int i = 0; i < 8; ++i) o[i] = (_Float16)acc[g * 8 + i];
    *(half8*)(hp + g * 8) = o;
  }
}

// ---------- pull-gather: one wave per dst node ----------
template <int MODE>
__global__ __launch_bounds__(256) void k_gather(const _Float16* __restrict__ h,
                                                const float* __restrict__ dis,
                                                const float2* __restrict__ edges,
                                                const int* __restrict__ rowptr,
                                                const float* __restrict__ b,
                                                const float* __restrict__ Wl,
                                                const float* __restrict__ bl,
                                                float* __restrict__ out, int n) {
  int lane = threadIdx.x & 63;
  int fl = lane & 7;    // feature group (features fl*8 .. fl*8+7)
  int eg = lane >> 3;   // edge group 0..7
  int node = blockIdx.x * 4 + (threadIdx.x >> 6);
  if (node >= n) return;
  int beg = rowptr[node], end = rowptr[node + 1];
  float s0 = dis[node];
  float acc[8];
#pragma unroll
  for (int i = 0; i < 8; ++i) acc[i] = 0.0f;

  for (int base = beg; base < end; base += 64) {
    int m = end - base; if (m > 64) m = 64;
    float2 pk = (lane < m) ? edges[base + lane] : make_float2(__int_as_float(0), 0.0f);
    float nrm = dis[__float_as_int(pk.x)] * pk.y * s0;
    int steps = (m + 7) >> 3;
    for (int s = 0; s < steps; ++s) {
      int j = s * 8 + eg;
      int   sj = __float_as_int(__shfl(pk.x, j));
      float nj = __shfl(nrm, j);
      half8 hv = *(const half8*)(h + (size_t)sj * 64 + fl * 8);
#pragma unroll
      for (int i = 0; i < 8; ++i) acc[i] = fmaf((float)hv[i], nj, acc[i]);
    }
  }
#pragma unroll
  for (int off = 8; off < 64; off <<= 1)
#pragma unroll
    for (int i = 0; i < 8; ++i) acc[i] += __shfl_xor(acc[i], off);

  half8 hs = *(const half8*)(h + (size_t)node * 64 + fl * 8);
  float4 bv0 = *(const float4*)(b + fl * 8);
  float4 bv1 = *(const float4*)(b + fl * 8 + 4);
  float bb[8] = {bv0.x, bv0.y, bv0.z, bv0.w, bv1.x, bv1.y, bv1.z, bv1.w};
  float s2 = s0 * s0;
#pragma unroll
  for (int i = 0; i < 8; ++i) acc[i] += bb[i] + (float)hs[i] * s2;

  if (MODE == 0) {
    if (eg == 0) {
      float4 o0 = make_float4(acc[0], acc[1], acc[2], acc[3]);
      float4 o1 = make_float4(acc[4], acc[5], acc[6], acc[7]);
      *(float4*)(out + (size_t)node * 64 + fl * 8) = o0;
      *(float4*)(out + (size_t)node * 64 + fl * 8 + 4) = o1;
    }
  } else {
    float4 wl0 = *(const float4*)(Wl + fl * 8);
    float4 wl1 = *(const float4*)(Wl + fl * 8 + 4);
    float wl[8] = {wl0.x, wl0.y, wl0.z, wl0.w, wl1.x, wl1.y, wl1.z, wl1.w};
    float v = 0.0f;
#pragma unroll
    for (int i = 0; i < 8; ++i) v += fmaxf(acc[i], 0.0f) * wl[i];
#pragma unroll
    for (int off = 1; off < 8; off <<= 1) v += __shfl_xor(v, off);
    if (lane == 0) out[node] = 1.0f / (1.0f + expf(-(v + bl[0])));
  }
}

extern "C" void kernel_launch(void* const* d_in, const int* in_sizes, int n_in,
                              void* d_out, int out_size, void* d_ws, size_t ws_size,
                              hipStream_t stream) {
  const float* X  = (const float*)d_in[0];
  const void*  EI = d_in[1];
  const float* EW = (const float*)d_in[2];
  const float* W1 = (const float*)d_in[3];
  const float* b1 = (const float*)d_in[4];
  const float* W2 = (const float*)d_in[5];
  const float* b2 = (const float*)d_in[6];
  const float* Wl = (const float*)d_in[7];
  const float* bl = (const float*)d_in[8];
  float* out = (float*)d_out;

  const int  n = in_sizes[0] / 128;      // 50000
  const long E = (long)in_sizes[1] / 2;  // 1,600,000

  const int chunk  = (int)((E + A2B - 1) / A2B);       // 3125 (<= STG)
  const int dwidth = (n + 255) / 256;                  // 196  (<= 256 for n <= 65536)
  const unsigned M = (unsigned)((0x100000000ULL + (unsigned)dwidth - 1) / (unsigned)dwidth);

  auto align = [](size_t x) { return (x + 255) & ~(size_t)255; };
  char* ws = (char*)d_ws;
  size_t off = 0;
  int*      flag    = (int*)(ws + off);      off += 256;
  float*    dis     = (float*)(ws + off);    off += align((size_t)n * 4);
  int*      rowptr  = (int*)(ws + off);      off += align((size_t)(n + 1) * 4);
  int*      bstart  = (int*)(ws + off);      off += align(257 * 4);
  unsigned* hist256 = (unsigned*)(ws + off); off += align((size_t)A2B * 256 * 4);
  unsigned* base256 = (unsigned*)(ws + off); off += align((size_t)A2B * 256 * 4);
  int4*     recs    = (int4*)(ws + off);     off += align((size_t)E * 16);
  float2*   edges   = (float2*)(ws + off);   off += align((size_t)E * 8);
  _Float16* A       = (_Float16*)(ws + off); off += align((size_t)n * 64 * 2);
  float*    B       = (float*)(ws + off);    off += align((size_t)n * 64 * 4);

  const int nbW = (n + 3) / 4;          // 4 waves/block gathers
  const int nbG = (n * 4 + 255) / 256;  // 4 threads/node GEMMs

  k_detect<<<1, 256, 0, stream>>>((const unsigned long long*)EI, flag);
  k_hist256<<<A2B, 256, 0, stream>>>(EI, flag, hist256, E, chunk, M);
  k_scan256<<<1, 256, 0, stream>>>(hist256, base256, bstart, E);
  k_bucket<<<A2B, A2T, 0, stream>>>(EI, flag, EW, base256, recs, E, chunk, M);
  k_build<<<256, 1024, 0, stream>>>(recs, bstart, rowptr, dis, edges, n, dwidth, E);

  // layer 1
  k_gemm1<<<nbG, dim3(256), 0, stream>>>(X, W1, A, n);
  k_gather<0><<<nbW, dim3(256), 0, stream>>>(A, dis, edges, rowptr, b1, Wl, bl, B, n);

  // layer 2 (relu fused into gemm2 read; readout fused into gather epilogue)
  k_gemm2<<<nbG, dim3(256), 0, stream>>>(B, W2, A, n);
  k_gather<1><<<nbW, dim3(256), 0, stream>>>(A, dis, edges, rowptr, b2, Wl, bl, out, n);
}